// Round 5
// baseline (239.042 us; speedup 1.0000x reference)
//
#include <hip/hip_runtime.h>

// EnergyFunction: B=2, S=2048, D=1024, H=8, hd=128
//   K = x@Wk^T, V = x@Wv^T, Sf = x@Wself^T   (bf16 intermediates)
//   att = softmax(-(K K^T)/sqrt(128), causal) @ V
//   out = (att + Sf) @ Wout^T                 (fp32 output)
//
// Split-K layout (ws >= 43MB):
//   0-8M   xb / O0part / Tb     8-16M  wkb,wvb,wsb (dead after gemm0) / O1part
//   16-24M Kb   24-32M Vtb([BH][128][2048])   32-40M Sbf
//   40-42M wob  42M+ Mp(256K), Lp(256K)
// Fallback layout (R3): as before, wob at 14M.
//
// R5 fix: every block-rendezvous is FULL_BARRIER (sched_barrier(0) fenced).
// Raw s_barrier is IntrNoMem in LLVM -> plain LDS reads were hoisted above it
// (R4 race: other waves' global_load_lds quarters not yet landed).

typedef unsigned short u16;
typedef short s16x8 __attribute__((ext_vector_type(8)));
typedef short s16x4 __attribute__((ext_vector_type(4)));
typedef unsigned short u16x4 __attribute__((ext_vector_type(4)));
typedef unsigned short u16x8 __attribute__((ext_vector_type(8)));
typedef float f32x4 __attribute__((ext_vector_type(4)));

#define DEV __device__ __forceinline__

DEV u16 f2bf(float f) {
    union { float f; unsigned u; } v; v.f = f;
    return (u16)((v.u + 0x7FFFu + ((v.u >> 16) & 1u)) >> 16);
}
DEV float bf2f(u16 h) {
    union { unsigned u; float f; } v; v.u = ((unsigned)h) << 16;
    return v.f;
}
DEV void gload16(const void* g, void* l) {
    __builtin_amdgcn_global_load_lds(
        (const __attribute__((address_space(1))) void*)g,
        (__attribute__((address_space(3))) void*)l, 16, 0, 0);
}

#define FULL_BARRIER()                          \
    do {                                        \
        __builtin_amdgcn_sched_barrier(0);      \
        __builtin_amdgcn_s_barrier();           \
        __builtin_amdgcn_sched_barrier(0);      \
    } while (0)

// ---------------- cast fp32 -> bf16 (x + 4 weights fused) ----------------
__global__ __launch_bounds__(256) void cast_all(
    const float* __restrict__ x, const float* __restrict__ wk,
    const float* __restrict__ wv, const float* __restrict__ wsf,
    const float* __restrict__ wo,
    u16* __restrict__ xb, u16* __restrict__ wkb, u16* __restrict__ wvb,
    u16* __restrict__ wsb, u16* __restrict__ wob) {
    int i = blockIdx.x * 256 + threadIdx.x;            // float4 index
    const int NX = (2 * 2048 * 1024) / 4;              // 1048576
    const int NW = (1024 * 1024) / 4;                  // 262144
    const float* src; u16* dst; int off;
    if (i < NX)              { src = x;   dst = xb;  off = i; }
    else if (i < NX + NW)    { src = wk;  dst = wkb; off = i - NX; }
    else if (i < NX + 2*NW)  { src = wv;  dst = wvb; off = i - NX - NW; }
    else if (i < NX + 3*NW)  { src = wsf; dst = wsb; off = i - NX - 2*NW; }
    else                     { src = wo;  dst = wob; off = i - NX - 3*NW; }
    float4 v = ((const float4*)src)[off];
    u16x4 o = { f2bf(v.x), f2bf(v.y), f2bf(v.z), f2bf(v.w) };
    ((u16x4*)dst)[off] = o;
}

// ---------------- NT GEMM: C[m][n] = sum_k A[m][k]*W[n][k] ----------------
// 128xBN tile, BK=32, 4 waves (2x2), 16x16x32 bf16 MFMA.
// 2-phase: one FULL_BARRIER per K-step; stage(t+1) issued right after the
// barrier, lands during compute(t); vmcnt(0) drained at top of t+1.
template <int MODE, int BN>
__global__ __launch_bounds__(256) void gemm_nt(
    const u16* __restrict__ A, const u16* __restrict__ W0,
    const u16* __restrict__ W1, const u16* __restrict__ W2,
    u16* __restrict__ O0, u16* __restrict__ O1, u16* __restrict__ O2,
    float* __restrict__ Of) {
    constexpr int NJ = BN / 32;                  // j-fragments per wave
    constexpr int BLOADS = (BN * 64) / 4096;     // per-wave B gloads (2 or 1)
    __shared__ __align__(16) u16 As[2][128 * 32];
    __shared__ __align__(16) u16 Bs[2][BN * 32];
    const int tid = threadIdx.x, lane = tid & 63, wave = tid >> 6;
    const int wr = wave >> 1, wc = wave & 1;
    const int m0 = blockIdx.y * 128, n0 = blockIdx.x * BN;
    const u16* Bw = W0;
    if (MODE == 0) Bw = (blockIdx.z == 0) ? W0 : (blockIdx.z == 1) ? W1 : W2;

    f32x4 acc[4][NJ];
#pragma unroll
    for (int i = 0; i < 4; ++i)
#pragma unroll
        for (int j = 0; j < NJ; ++j) acc[i][j] = f32x4{0.f, 0.f, 0.f, 0.f};

    // staging geometry: A tile [128][32] (64B rows), B tile [BN][32]
    const int o1 = wave * 1024 + lane * 16;
    const int r1 = o1 >> 6, c1 = (o1 & 63) >> 1;
    const int o2 = o1 + 4096;
    const int r2 = o2 >> 6, c2 = (o2 & 63) >> 1;

    auto stage = [&](int k0, int buf) {
        gload16(A + ((size_t)(m0 + r1) << 10) + k0 + c1, (char*)As[buf] + wave * 1024);
        gload16(A + ((size_t)(m0 + r2) << 10) + k0 + c2, (char*)As[buf] + 4096 + wave * 1024);
        gload16(Bw + ((size_t)(n0 + r1) << 10) + k0 + c1, (char*)Bs[buf] + wave * 1024);
        if constexpr (BLOADS == 2)
            gload16(Bw + ((size_t)(n0 + r2) << 10) + k0 + c2, (char*)Bs[buf] + 4096 + wave * 1024);
    };

    stage(0, 0);
    for (int t = 0; t < 32; ++t) {
        const int cur = t & 1;
        asm volatile("s_waitcnt vmcnt(0)" ::: "memory");  // tile t landed (mine)
        FULL_BARRIER();                                    // ...and everyone's
        if (t < 31) stage((t + 1) << 5, cur ^ 1);          // flies under compute
        const int kb = (lane >> 4) << 3;
        s16x8 af[4], bfr[NJ];
#pragma unroll
        for (int i = 0; i < 4; ++i)
            af[i] = *(const s16x8*)&As[cur][(wr * 64 + i * 16 + (lane & 15)) * 32 + kb];
#pragma unroll
        for (int j = 0; j < NJ; ++j)
            bfr[j] = *(const s16x8*)&Bs[cur][(wc * (BN / 2) + j * 16 + (lane & 15)) * 32 + kb];
#pragma unroll
        for (int i = 0; i < 4; ++i)
#pragma unroll
            for (int j = 0; j < NJ; ++j)
                acc[i][j] = __builtin_amdgcn_mfma_f32_16x16x32_bf16(af[i], bfr[j], acc[i][j], 0, 0, 0);
    }

    // epilogue: C/D layout col=lane&15 (n), row=(lane>>4)*4+reg (m)
    const int mb0 = m0 + wr * 64, nb0 = n0 + wc * (BN / 2);
    if (MODE == 1) {
#pragma unroll
        for (int i = 0; i < 4; ++i)
#pragma unroll
            for (int j = 0; j < NJ; ++j) {
                int n = nb0 + j * 16 + (lane & 15);
                int mbase = mb0 + i * 16 + ((lane >> 4) << 2);
#pragma unroll
                for (int r = 0; r < 4; ++r)
                    Of[((size_t)(mbase + r) << 10) + n] = acc[i][j][r];
            }
    } else if (blockIdx.z == 1) {
        // V: write transposed per head: Vt[(b*8+h)*128 + d][s]
#pragma unroll
        for (int i = 0; i < 4; ++i)
#pragma unroll
            for (int j = 0; j < NJ; ++j) {
                int n = nb0 + j * 16 + (lane & 15);
                int h = n >> 7, d = n & 127;
                int mbase = mb0 + i * 16 + ((lane >> 4) << 2);
                int b = mbase >> 11, s = mbase & 2047;
                u16x4 pk;
#pragma unroll
                for (int r = 0; r < 4; ++r) pk[r] = f2bf(acc[i][j][r]);
                *(u16x4*)(O1 + (((size_t)(b * 8 + h) << 7) + d) * 2048 + s) = pk;
            }
    } else {
        u16* dst = blockIdx.z ? O2 : O0;
#pragma unroll
        for (int i = 0; i < 4; ++i)
#pragma unroll
            for (int j = 0; j < NJ; ++j) {
                int n = nb0 + j * 16 + (lane & 15);
                int mbase = mb0 + i * 16 + ((lane >> 4) << 2);
#pragma unroll
                for (int r = 0; r < 4; ++r)
                    dst[((size_t)(mbase + r) << 10) + n] = f2bf(acc[i][j][r]);
            }
    }
}

// ---------------- split-K causal flash attention ----------------
// grid (64, 16): bx -> (q_raw = bx>>1, half = bx&1); qt remapped by bh bit2 so
// co-resident blocks (id+=256 <-> bh+=4) pair to a constant 33 iters.
// KVBLK=32, dbuf LDS = 32KB -> 4 blocks/CU -> 4 waves/SIMD.
// Unnormalized O + (m,l) partials to ws; finite sentinels (no -inf NaNs).
#define MINIT (-30000.0f)
#define MASKV (-60000.0f)
__global__ __launch_bounds__(256, 4) void attn_split(
    const u16* __restrict__ Kb, const u16* __restrict__ Vtb,
    u16* __restrict__ Op0, u16* __restrict__ Op1,
    float* __restrict__ Mp, float* __restrict__ Lp) {
    __shared__ __align__(16) u16 Ks[2][32 * 128];   // K tile [k][d], 256B rows, swz (r&7)<<4
    __shared__ __align__(16) u16 Vs[2][128 * 32];   // V^T tile [d][k], 64B rows, swz (d&3)<<4
    const int tid = threadIdx.x, lane = tid & 63, wave = tid >> 6;
    const int q_raw = blockIdx.x >> 1, half = blockIdx.x & 1;
    const int bh = blockIdx.y, b = bh >> 3, h = bh & 7;
    const int qt = ((bh >> 2) & 1) ? q_raw : (31 - q_raw);
    const int hi = lane >> 4, lo = lane & 15;
    const int qrow = qt * 64 + wave * 16 + lo;      // this lane's P-column q

    s16x8 qf[4];
    {
        const u16* qp = Kb + ((size_t)(b * 2048 + qrow) << 10) + h * 128 + (hi << 3);
#pragma unroll
        for (int c = 0; c < 4; ++c) qf[c] = *(const s16x8*)(qp + c * 32);
    }

    // staging: 2 chunks/wave for K (8KB tile) and V (8KB tile)
    const u16* ksrc[2];
    const u16* vsrc[2];
    int ldst[2];
#pragma unroll
    for (int jj = 0; jj < 2; ++jj) {
        int p = wave * 2048 + jj * 1024 + lane * 16;  // linear byte pos in 8KB tile
        ldst[jj] = wave * 2048 + jj * 1024;
        int rk = p >> 8, cbs = (p & 255) ^ ((rk & 7) << 4);
        ksrc[jj] = Kb + ((size_t)(b * 2048 + rk) << 10) + h * 128 + (cbs >> 1);
        int dv = p >> 6, kbs = (p & 63) ^ ((dv & 3) << 4);
        vsrc[jj] = Vtb + (((size_t)(bh * 128 + dv)) << 11) + (kbs >> 1);
    }
    auto stage = [&](int ks0, int buf) {
        char* kb = (char*)Ks[buf];
        char* vb = (char*)Vs[buf];
#pragma unroll
        for (int jj = 0; jj < 2; ++jj) {
            gload16(ksrc[jj] + ((size_t)ks0 << 10), kb + ldst[jj]);
            gload16(vsrc[jj] + ks0, vb + ldst[jj]);
        }
    };

    f32x4 oacc[8];
#pragma unroll
    for (int nf = 0; nf < 8; ++nf) oacc[nf] = f32x4{0.f, 0.f, 0.f, 0.f};
    float mrun = MINIT, lrun = 0.f;
    const float SC = -0.12751741566723328f;  // -log2(e)/sqrt(128)

    const int j0 = half ? (qt + 1) : 0;
    const int j1 = j0 + qt + 1;

    stage(j0 << 5, 0);
    for (int j = j0; j < j1; ++j) {
        const int cur = (j - j0) & 1;
        asm volatile("s_waitcnt vmcnt(0)" ::: "memory");  // tile j landed (mine)
        FULL_BARRIER();                                    // ...and everyone's
        if (j + 1 < j1) stage((j + 1) << 5, cur ^ 1);     // flies under compute

        // QK^T (swapped): sf[mf] reg r = score[k = j*32 + mf*16 + hi*4 + r][q=lo]
        f32x4 sf[2];
        __builtin_amdgcn_s_setprio(1);
#pragma unroll
        for (int mf = 0; mf < 2; ++mf) {
            f32x4 s = {0.f, 0.f, 0.f, 0.f};
            int kr = mf * 16 + lo;
            const char* rowp = (const char*)Ks[cur] + kr * 256;
            int swz = (kr & 7) << 4;
#pragma unroll
            for (int c = 0; c < 4; ++c) {
                s16x8 kf = *(const s16x8*)(rowp + ((c * 64 + hi * 16) ^ swz));
                s = __builtin_amdgcn_mfma_f32_16x16x32_bf16(kf, qf[c], s, 0, 0, 0);
            }
            sf[mf] = s;
        }
        __builtin_amdgcn_s_setprio(0);

        const bool diag = (j >= 2 * qt);
        float p[2][4];
        float pm = MASKV;
#pragma unroll
        for (int mf = 0; mf < 2; ++mf)
#pragma unroll
            for (int r = 0; r < 4; ++r) {
                float sv = sf[mf][r] * SC;
                if (diag) {
                    int kg = j * 32 + mf * 16 + (hi << 2) + r;
                    if (kg > qrow) sv = MASKV;
                }
                p[mf][r] = sv;
                pm = fmaxf(pm, sv);
            }
        pm = fmaxf(pm, __shfl_xor(pm, 16));
        pm = fmaxf(pm, __shfl_xor(pm, 32));

        // defer-rescale: skip O-rescale when max didn't grow
        const bool grow = !__all(pm <= mrun);
        float mnew = mrun;
        if (grow) {
            mnew = fmaxf(mrun, pm);
            float corr = exp2f(mrun - mnew);
            lrun *= corr;
            float cr[4];
#pragma unroll
            for (int r = 0; r < 4; ++r) cr[r] = __shfl(corr, (hi << 2) + r);
#pragma unroll
            for (int nf = 0; nf < 8; ++nf)
#pragma unroll
                for (int r = 0; r < 4; ++r) oacc[nf][r] *= cr[r];
            mrun = mnew;
        }

        float psum = 0.f;
        float p2[2][4];
#pragma unroll
        for (int mf = 0; mf < 2; ++mf)
#pragma unroll
            for (int r = 0; r < 4; ++r) {
                float e = exp2f(p[mf][r] - mnew);
                p2[mf][r] = e;
                psum += e;
            }
        psum += __shfl_xor(psum, 16);
        psum += __shfl_xor(psum, 32);
        lrun += psum;

        // pack P as PV A-operand; k-bijection slot i -> k = hi*4 + (i&3) + 16*(i>>2)
        s16x8 pa;
#pragma unroll
        for (int e = 0; e < 4; ++e) pa[e] = (short)f2bf(p2[0][e]);
#pragma unroll
        for (int e = 0; e < 4; ++e) pa[4 + e] = (short)f2bf(p2[1][e]);

        // PV: B-frag slot i reads Vs[d][same k-bijection]
        __builtin_amdgcn_s_setprio(1);
#pragma unroll
        for (int nf = 0; nf < 8; ++nf) {
            int d = nf * 16 + lo;
            const char* vrow = (const char*)Vs[cur] + d * 64;
            int swz = (d & 3) << 4;
            int ob = hi << 3;
            s16x4 vlo = *(const s16x4*)(vrow + (ob ^ swz));
            s16x4 vhi = *(const s16x4*)(vrow + ((ob + 32) ^ swz));
            s16x8 vf = {vlo[0], vlo[1], vlo[2], vlo[3], vhi[0], vhi[1], vhi[2], vhi[3]};
            oacc[nf] = __builtin_amdgcn_mfma_f32_16x16x32_bf16(pa, vf, oacc[nf], 0, 0, 0);
        }
        __builtin_amdgcn_s_setprio(0);
    }

    // epilogue: write unnormalized partial O (bf16) + m,l (f32)
    if (hi == 0) {
        int mi = (half * 16 + bh) * 2048 + qrow;
        Mp[mi] = mrun;
        Lp[mi] = lrun;
    }
    u16* Op = half ? Op1 : Op0;
#pragma unroll
    for (int nf = 0; nf < 8; ++nf) {
        int d = nf * 16 + lo;
#pragma unroll
        for (int r = 0; r < 4; ++r) {
            int q2 = qt * 64 + wave * 16 + (hi << 2) + r;
            Op[((size_t)(b * 2048 + q2) << 10) + h * 128 + d] = f2bf(oacc[nf][r]);
        }
    }
}

// ---------------- combine partials + self-force -> Tb ----------------
__global__ __launch_bounds__(256) void attn_combine(
    const u16* __restrict__ O0, const u16* __restrict__ O1,
    const float* __restrict__ Mp, const float* __restrict__ Lp,
    const u16* __restrict__ Sb, u16* __restrict__ Tb) {
    int i = blockIdx.x * 256 + threadIdx.x;      // 524288 threads, 8 elems each
    int d0 = (i & 15) << 3;
    int row = i >> 4;                            // (b*2048+q)*8 + h
    int h = row & 7;
    int bq = row >> 3;                           // b*2048+q
    int b = bq >> 11, q = bq & 2047;
    int bh = b * 8 + h;
    int mi0 = bh * 2048 + q, mi1 = (16 + bh) * 2048 + q;
    float m0 = Mp[mi0], m1 = Mp[mi1], l0 = Lp[mi0], l1 = Lp[mi1];
    float m = fmaxf(m0, m1);
    float a0 = exp2f(m0 - m), a1 = exp2f(m1 - m);
    float rd = 1.0f / (l0 * a0 + l1 * a1);
    size_t base = ((size_t)bq << 10) + (h << 7) + d0;
    s16x8 o0 = *(const s16x8*)(O0 + base);
    s16x8 o1 = *(const s16x8*)(O1 + base);
    s16x8 sf = *(const s16x8*)(Sb + base);
    u16x8 out;
#pragma unroll
    for (int e = 0; e < 8; ++e)
        out[e] = f2bf((bf2f((u16)o0[e]) * a0 + bf2f((u16)o1[e]) * a1) * rd + bf2f((u16)sf[e]));
    *(u16x8*)(Tb + base) = out;
}

// ---------------- fallback attention (R3, ws < 43MB) ----------------
__global__ __launch_bounds__(256) void attn_kernel(
    const u16* __restrict__ Kb, const u16* __restrict__ Vtb,
    const u16* __restrict__ Sb, u16* __restrict__ Tb) {
    __shared__ __align__(16) u16 Ks[2][64 * 128];
    __shared__ __align__(16) u16 Vs[2][128 * 64];
    const int tid = threadIdx.x, lane = tid & 63, wave = tid >> 6;
    const int qt = (blockIdx.y & 8) ? blockIdx.x : (31 - blockIdx.x);
    const int bh = blockIdx.y, b = bh >> 3, h = bh & 7;
    const int hi = lane >> 4, lo = lane & 15;
    const int qlocal = wave * 16 + lo;
    const int qrow = qt * 64 + qlocal;

    s16x8 qf[4];
    {
        const u16* qp = Kb + ((size_t)(b * 2048 + qrow) << 10) + h * 128 + (hi << 3);
#pragma unroll
        for (int c = 0; c < 4; ++c) qf[c] = *(const s16x8*)(qp + c * 32);
    }
    const u16* ksrcb[4];
    const u16* vsrcb[4];
    int ldst[4];
#pragma unroll
    for (int j = 0; j < 4; ++j) {
        int p = wave * 4096 + j * 1024 + lane * 16;
        ldst[j] = wave * 4096 + j * 1024;
        int rk = p >> 8, cbs = (p & 255) ^ ((rk & 7) << 4);
        ksrcb[j] = Kb + ((size_t)(b * 2048 + rk) << 10) + h * 128 + (cbs >> 1);
        int dv = p >> 7, kbs = (p & 127) ^ ((dv & 7) << 4);
        vsrcb[j] = Vtb + (((size_t)(bh * 128 + dv)) << 11) + (kbs >> 1);
    }
    auto stage = [&](int ks0, int buf) {
        char* kb = (char*)Ks[buf];
        char* vb = (char*)Vs[buf];
#pragma unroll
        for (int j = 0; j < 4; ++j) {
            gload16(ksrcb[j] + ((size_t)ks0 << 10), kb + ldst[j]);
            gload16(vsrcb[j] + ks0, vb + ldst[j]);
        }
    };
    f32x4 oacc[8];
#pragma unroll
    for (int nf = 0; nf < 8; ++nf) oacc[nf] = f32x4{0.f, 0.f, 0.f, 0.f};
    float mrun = -__builtin_inff(), lrun = 0.f;
    const float SC = -0.12751741566723328f;

    stage(0, 0);
    asm volatile("s_waitcnt vmcnt(0)" ::: "memory");
    FULL_BARRIER();
    for (int kt = 0; kt <= qt; ++kt) {
        const int cur = kt & 1;
        if (kt < qt) {
            stage((kt + 1) << 6, cur ^ 1);
            asm volatile("s_waitcnt vmcnt(8)" ::: "memory");
        } else {
            asm volatile("s_waitcnt vmcnt(0)" ::: "memory");
        }
        FULL_BARRIER();
        f32x4 sf[4];
        __builtin_amdgcn_s_setprio(1);
#pragma unroll
        for (int mf = 0; mf < 4; ++mf) {
            f32x4 s = {0.f, 0.f, 0.f, 0.f};
            int kr = mf * 16 + lo;
            const char* rowp = (const char*)Ks[cur] + kr * 256;
            int swz = (kr & 7) << 4;
#pragma unroll
            for (int c = 0; c < 4; ++c) {
                s16x8 kf = *(const s16x8*)(rowp + ((c * 64 + hi * 16) ^ swz));
                s = __builtin_amdgcn_mfma_f32_16x16x32_bf16(kf, qf[c], s, 0, 0, 0);
            }
            sf[mf] = s;
        }
        __builtin_amdgcn_s_setprio(0);
        const bool diag = (kt == qt);
        float p[4][4];
        float pm = -__builtin_inff();
#pragma unroll
        for (int mf = 0; mf < 4; ++mf)
#pragma unroll
            for (int r = 0; r < 4; ++r) {
                float sv = sf[mf][r] * SC;
                if (diag) {
                    int klocal = mf * 16 + (hi << 2) + r;
                    if (klocal > qlocal) sv = -__builtin_inff();
                }
                p[mf][r] = sv;
                pm = fmaxf(pm, sv);
            }
        pm = fmaxf(pm, __shfl_xor(pm, 16));
        pm = fmaxf(pm, __shfl_xor(pm, 32));
        const bool grow = !__all(pm <= mrun);
        float mnew = grow ? fmaxf(mrun, pm) : mrun;
        if (grow) {
            float corr = exp2f(mrun - mnew);
            lrun *= corr;
            float cr[4];
#pragma unroll
            for (int r = 0; r < 4; ++r) cr[r] = __shfl(corr, (hi << 2) + r);
#pragma unroll
            for (int nf = 0; nf < 8; ++nf)
#pragma unroll
                for (int r = 0; r < 4; ++r) oacc[nf][r] *= cr[r];
            mrun = mnew;
        }
        float psum = 0.f;
        float p2[4][4];
#pragma unroll
        for (int mf = 0; mf < 4; ++mf)
#pragma unroll
            for (int r = 0; r < 4; ++r) {
                float e = exp2f(p[mf][r] - mnew);
                p2[mf][r] = e;
                psum += e;
            }
        psum += __shfl_xor(psum, 16);
        psum += __shfl_xor(psum, 32);
        lrun += psum;
        s16x8 pa[2];
#pragma unroll
        for (int c2 = 0; c2 < 2; ++c2) {
            s16x8 t;
#pragma unroll
            for (int e = 0; e < 4; ++e) t[e] = (short)f2bf(p2[2 * c2][e]);
#pragma unroll
            for (int e = 0; e < 4; ++e) t[4 + e] = (short)f2bf(p2[2 * c2 + 1][e]);
            pa[c2] = t;
        }
        __builtin_amdgcn_s_setprio(1);
#pragma unroll
        for (int nf = 0; nf < 8; ++nf) {
            int d = nf * 16 + lo;
            const char* vrow = (const char*)Vs[cur] + d * 128;
            int swz = (d & 7) << 4;
#pragma unroll
            for (int c2 = 0; c2 < 2; ++c2) {
                int ob = (hi << 3) + (c2 << 6);
                s16x4 vlo = *(const s16x4*)(vrow + (ob ^ swz));
                s16x4 vhi = *(const s16x4*)(vrow + ((ob + 32) ^ swz));
                s16x8 vf = {vlo[0], vlo[1], vlo[2], vlo[3], vhi[0], vhi[1], vhi[2], vhi[3]};
                oacc[nf] = __builtin_amdgcn_mfma_f32_16x16x32_bf16(pa[c2], vf, oacc[nf], 0, 0, 0);
            }
        }
        __builtin_amdgcn_s_setprio(0);
        FULL_BARRIER();
    }
    float linv[4];
#pragma unroll
    for (int r = 0; r < 4; ++r) linv[r] = 1.0f / __shfl(lrun, (hi << 2) + r);
#pragma unroll
    for (int nf = 0; nf < 8; ++nf) {
        int d = nf * 16 + lo;
#pragma unroll
        for (int r = 0; r < 4; ++r) {
            int q2 = qt * 64 + wave * 16 + (hi << 2) + r;
            size_t idx = ((size_t)(b * 2048 + q2) << 10) + h * 128 + d;
            Tb[idx] = f2bf(oacc[nf][r] * linv[r] + bf2f(Sb[idx]));
        }
    }
}

// ---------------- launch ----------------
extern "C" void kernel_launch(void* const* d_in, const int* in_sizes, int n_in,
                              void* d_out, int out_size, void* d_ws, size_t ws_size,
                              hipStream_t stream) {
    const float* x   = (const float*)d_in[0];
    const float* Wk  = (const float*)d_in[1];
    const float* Wv  = (const float*)d_in[2];
    const float* Wsf = (const float*)d_in[3];
    const float* Wo  = (const float*)d_in[4];
    float* out = (float*)d_out;
    char* ws = (char*)d_ws;
    u16* xb  = (u16*)(ws);                       // 8 MB (also O0part / Tb)
    u16* wkb = (u16*)(ws + (8u << 20));
    u16* wvb = (u16*)(ws + (10u << 20));
    u16* wsb = (u16*)(ws + (12u << 20));
    u16* Kb  = (u16*)(ws + (16u << 20));         // 8 MB
    u16* Vtb = (u16*)(ws + (24u << 20));         // 8 MB, [BH][128][2048]
    u16* Sbf = (u16*)(ws + (32u << 20));         // 8 MB
    u16* Tb  = xb;

    const bool split = ws_size >= ((size_t)43u << 20);

    if (split) {
        u16* wob   = (u16*)(ws + (40u << 20));   // 2 MB
        u16* Op0   = xb;                         // 8 MB (aliases xb/Tb)
        u16* Op1   = (u16*)(ws + (8u << 20));    // 8 MB (over dead wkb/wvb/wsb)
        float* Mp  = (float*)(ws + (42u << 20)); // 256 KB
        float* Lp  = (float*)(ws + (42u << 20) + (256u << 10));
        cast_all<<<8192, 256, 0, stream>>>(x, Wk, Wv, Wsf, Wo, xb, wkb, wvb, wsb, wob);
        gemm_nt<0, 128><<<dim3(8, 32, 3), 256, 0, stream>>>(xb, wkb, wvb, wsb, Kb, Vtb, Sbf, nullptr);
        attn_split<<<dim3(64, 16), 256, 0, stream>>>(Kb, Vtb, Op0, Op1, Mp, Lp);
        attn_combine<<<2048, 256, 0, stream>>>(Op0, Op1, Mp, Lp, Sbf, Tb);
        gemm_nt<1, 64><<<dim3(16, 32, 1), 256, 0, stream>>>(Tb, wob, nullptr, nullptr,
                                                            nullptr, nullptr, nullptr, out);
    } else {
        u16* wob = (u16*)(ws + (14u << 20));
        cast_all<<<8192, 256, 0, stream>>>(x, Wk, Wv, Wsf, Wo, xb, wkb, wvb, wsb, wob);
        gemm_nt<0, 128><<<dim3(8, 32, 3), 256, 0, stream>>>(xb, wkb, wvb, wsb, Kb, Vtb, Sbf, nullptr);
        attn_kernel<<<dim3(32, 16), 256, 0, stream>>>(Kb, Vtb, Sbf, Tb);
        gemm_nt<1, 64><<<dim3(16, 32, 1), 256, 0, stream>>>(Tb, wob, nullptr, nullptr,
                                                            nullptr, nullptr, nullptr, out);
    }
}

// Round 6
// 228.135 us; speedup vs baseline: 1.0478x; 1.0478x over previous
//
#include <hip/hip_runtime.h>

// EnergyFunction: B=2, S=2048, D=1024, H=8, hd=128
//   K = x@Wk^T, V = x@Wv^T, Sf = x@Wself^T   (bf16 intermediates)
//   att = softmax(-(K K^T)/sqrt(128), causal) @ V
//   out = (att + Sf) @ Wout^T                 (fp32 output)
//
// Split-K layout (ws >= 43MB):
//   0-8M   xb / O0part / Tb     8-16M  wkb,wvb,wsb (dead after gemm0) / O1part
//   16-24M Kb   24-32M Vtb([BH][128][2048])   32-40M Sbf
//   40-42M wob  42M+ Mp(256K), Lp(256K)
//
// R6: GEMM = prefetch-distance-2 triple-buffer with counted vmcnt (never 0
// mid-loop); attn P-pack via v_cvt_pk_bf16_f32 (4 asm ops replace ~40 VALU).

typedef unsigned short u16;
typedef short s16x8 __attribute__((ext_vector_type(8)));
typedef short s16x4 __attribute__((ext_vector_type(4)));
typedef unsigned short u16x4 __attribute__((ext_vector_type(4)));
typedef unsigned short u16x8 __attribute__((ext_vector_type(8)));
typedef float f32x4 __attribute__((ext_vector_type(4)));

#define DEV __device__ __forceinline__

DEV u16 f2bf(float f) {
    union { float f; unsigned u; } v; v.f = f;
    return (u16)((v.u + 0x7FFFu + ((v.u >> 16) & 1u)) >> 16);
}
DEV float bf2f(u16 h) {
    union { unsigned u; float f; } v; v.u = ((unsigned)h) << 16;
    return v.f;
}
DEV void gload16(const void* g, void* l) {
    __builtin_amdgcn_global_load_lds(
        (const __attribute__((address_space(1))) void*)g,
        (__attribute__((address_space(3))) void*)l, 16, 0, 0);
}

#define FULL_BARRIER()                          \
    do {                                        \
        __builtin_amdgcn_sched_barrier(0);      \
        __builtin_amdgcn_s_barrier();           \
        __builtin_amdgcn_sched_barrier(0);      \
    } while (0)

// ---------------- cast fp32 -> bf16 (x + 4 weights fused) ----------------
__global__ __launch_bounds__(256) void cast_all(
    const float* __restrict__ x, const float* __restrict__ wk,
    const float* __restrict__ wv, const float* __restrict__ wsf,
    const float* __restrict__ wo,
    u16* __restrict__ xb, u16* __restrict__ wkb, u16* __restrict__ wvb,
    u16* __restrict__ wsb, u16* __restrict__ wob) {
    int i = blockIdx.x * 256 + threadIdx.x;            // float4 index
    const int NX = (2 * 2048 * 1024) / 4;              // 1048576
    const int NW = (1024 * 1024) / 4;                  // 262144
    const float* src; u16* dst; int off;
    if (i < NX)              { src = x;   dst = xb;  off = i; }
    else if (i < NX + NW)    { src = wk;  dst = wkb; off = i - NX; }
    else if (i < NX + 2*NW)  { src = wv;  dst = wvb; off = i - NX - NW; }
    else if (i < NX + 3*NW)  { src = wsf; dst = wsb; off = i - NX - 2*NW; }
    else                     { src = wo;  dst = wob; off = i - NX - 3*NW; }
    float4 v = ((const float4*)src)[off];
    u16x4 o = { f2bf(v.x), f2bf(v.y), f2bf(v.z), f2bf(v.w) };
    ((u16x4*)dst)[off] = o;
}

// ---------------- NT GEMM: C[m][n] = sum_k A[m][k]*W[n][k] ----------------
// 128xBN tile, BK=32, 4 waves (2x2), 16x16x32 bf16 MFMA.
// Prefetch-distance-2, TRIPLE-buffered LDS, counted vmcnt(NL) (never 0 in
// the main loop): tile t's loads precede tile t+1's in issue order, so
// vmcnt(NL) implies tile t landed while t+1's NL loads stay in flight.
// Issue->drain distance = 2 compute phases + 2 barriers ~ covers HBM latency.
template <int MODE, int BN>
__global__ __launch_bounds__(256) void gemm_nt(
    const u16* __restrict__ A, const u16* __restrict__ W0,
    const u16* __restrict__ W1, const u16* __restrict__ W2,
    u16* __restrict__ O0, u16* __restrict__ O1, u16* __restrict__ O2,
    float* __restrict__ Of) {
    constexpr int NJ = BN / 32;                  // j-fragments per wave
    constexpr int BLOADS = (BN * 64) / 4096;     // per-wave B gloads (2 or 1)
    __shared__ __align__(16) u16 As[3][128 * 32];
    __shared__ __align__(16) u16 Bs[3][BN * 32];
    const int tid = threadIdx.x, lane = tid & 63, wave = tid >> 6;
    const int wr = wave >> 1, wc = wave & 1;
    const int m0 = blockIdx.y * 128, n0 = blockIdx.x * BN;
    const u16* Bw = W0;
    if (MODE == 0) Bw = (blockIdx.z == 0) ? W0 : (blockIdx.z == 1) ? W1 : W2;

    f32x4 acc[4][NJ];
#pragma unroll
    for (int i = 0; i < 4; ++i)
#pragma unroll
        for (int j = 0; j < NJ; ++j) acc[i][j] = f32x4{0.f, 0.f, 0.f, 0.f};

    // staging geometry: A tile [128][32] (64B rows), B tile [BN][32]
    const int o1 = wave * 1024 + lane * 16;
    const int r1 = o1 >> 6, c1 = (o1 & 63) >> 1;
    const int o2 = o1 + 4096;
    const int r2 = o2 >> 6, c2 = (o2 & 63) >> 1;

    auto stage = [&](int k0, int buf) {
        char* ab = (char*)As + buf * 8192;
        char* bb = (char*)Bs + buf * (BN * 64);
        gload16(A + ((size_t)(m0 + r1) << 10) + k0 + c1, ab + wave * 1024);
        gload16(A + ((size_t)(m0 + r2) << 10) + k0 + c2, ab + 4096 + wave * 1024);
        gload16(Bw + ((size_t)(n0 + r1) << 10) + k0 + c1, bb + wave * 1024);
        if constexpr (BLOADS == 2)
            gload16(Bw + ((size_t)(n0 + r2) << 10) + k0 + c2, bb + 4096 + wave * 1024);
    };

    stage(0, 0);
    stage(32, 1);
    int cur = 0;
    for (int t = 0; t < 32; ++t) {
        if (t < 31) {
            // allow tile t+1's loads (2+BLOADS) to stay outstanding
            if constexpr (BLOADS == 2)
                asm volatile("s_waitcnt vmcnt(4)" ::: "memory");
            else
                asm volatile("s_waitcnt vmcnt(3)" ::: "memory");
        } else {
            asm volatile("s_waitcnt vmcnt(0)" ::: "memory");
        }
        FULL_BARRIER();                                   // tile t landed for all
        if (t + 2 < 32) {
            int nb = cur + 2; if (nb >= 3) nb -= 3;
            stage((t + 2) << 5, nb);                      // overwrites tile t-1's buf
        }
        const int kb = (lane >> 4) << 3;
        const u16* Ac = As[0] + cur * 4096;
        const u16* Bc = Bs[0] + cur * (BN * 32);
        s16x8 af[4], bfr[NJ];
#pragma unroll
        for (int i = 0; i < 4; ++i)
            af[i] = *(const s16x8*)&Ac[(wr * 64 + i * 16 + (lane & 15)) * 32 + kb];
#pragma unroll
        for (int j = 0; j < NJ; ++j)
            bfr[j] = *(const s16x8*)&Bc[(wc * (BN / 2) + j * 16 + (lane & 15)) * 32 + kb];
#pragma unroll
        for (int i = 0; i < 4; ++i)
#pragma unroll
            for (int j = 0; j < NJ; ++j)
                acc[i][j] = __builtin_amdgcn_mfma_f32_16x16x32_bf16(af[i], bfr[j], acc[i][j], 0, 0, 0);
        ++cur; if (cur == 3) cur = 0;
    }

    // epilogue: C/D layout col=lane&15 (n), row=(lane>>4)*4+reg (m)
    const int mb0 = m0 + wr * 64, nb0 = n0 + wc * (BN / 2);
    if (MODE == 1) {
#pragma unroll
        for (int i = 0; i < 4; ++i)
#pragma unroll
            for (int j = 0; j < NJ; ++j) {
                int n = nb0 + j * 16 + (lane & 15);
                int mbase = mb0 + i * 16 + ((lane >> 4) << 2);
#pragma unroll
                for (int r = 0; r < 4; ++r)
                    Of[((size_t)(mbase + r) << 10) + n] = acc[i][j][r];
            }
    } else if (blockIdx.z == 1) {
        // V: write transposed per head: Vt[(b*8+h)*128 + d][s]
#pragma unroll
        for (int i = 0; i < 4; ++i)
#pragma unroll
            for (int j = 0; j < NJ; ++j) {
                int n = nb0 + j * 16 + (lane & 15);
                int h = n >> 7, d = n & 127;
                int mbase = mb0 + i * 16 + ((lane >> 4) << 2);
                int b = mbase >> 11, s = mbase & 2047;
                u16x4 pk;
#pragma unroll
                for (int r = 0; r < 4; ++r) pk[r] = f2bf(acc[i][j][r]);
                *(u16x4*)(O1 + (((size_t)(b * 8 + h) << 7) + d) * 2048 + s) = pk;
            }
    } else {
        u16* dst = blockIdx.z ? O2 : O0;
#pragma unroll
        for (int i = 0; i < 4; ++i)
#pragma unroll
            for (int j = 0; j < NJ; ++j) {
                int n = nb0 + j * 16 + (lane & 15);
                int mbase = mb0 + i * 16 + ((lane >> 4) << 2);
#pragma unroll
                for (int r = 0; r < 4; ++r)
                    dst[((size_t)(mbase + r) << 10) + n] = f2bf(acc[i][j][r]);
            }
    }
}

// ---------------- split-K causal flash attention ----------------
// grid (64, 16): bx -> (q_raw = bx>>1, half = bx&1); qt remapped by bh bit2 so
// co-resident blocks pair to constant total iterations. KVBLK=32, dbuf LDS =
// 32KB -> 4 blocks/CU. Unnormalized O + (m,l) partials; finite sentinels.
#define MINIT (-30000.0f)
#define MASKV (-60000.0f)
__global__ __launch_bounds__(256, 4) void attn_split(
    const u16* __restrict__ Kb, const u16* __restrict__ Vtb,
    u16* __restrict__ Op0, u16* __restrict__ Op1,
    float* __restrict__ Mp, float* __restrict__ Lp) {
    __shared__ __align__(16) u16 Ks[2][32 * 128];   // K tile [k][d], 256B rows, swz (r&7)<<4
    __shared__ __align__(16) u16 Vs[2][128 * 32];   // V^T tile [d][k], 64B rows, swz (d&3)<<4
    const int tid = threadIdx.x, lane = tid & 63, wave = tid >> 6;
    const int q_raw = blockIdx.x >> 1, half = blockIdx.x & 1;
    const int bh = blockIdx.y, b = bh >> 3, h = bh & 7;
    const int qt = ((bh >> 2) & 1) ? q_raw : (31 - q_raw);
    const int hi = lane >> 4, lo = lane & 15;
    const int qrow = qt * 64 + wave * 16 + lo;      // this lane's P-column q

    s16x8 qf[4];
    {
        const u16* qp = Kb + ((size_t)(b * 2048 + qrow) << 10) + h * 128 + (hi << 3);
#pragma unroll
        for (int c = 0; c < 4; ++c) qf[c] = *(const s16x8*)(qp + c * 32);
    }

    // staging: 2 chunks/wave for K (8KB tile) and V (8KB tile)
    const u16* ksrc[2];
    const u16* vsrc[2];
    int ldst[2];
#pragma unroll
    for (int jj = 0; jj < 2; ++jj) {
        int p = wave * 2048 + jj * 1024 + lane * 16;  // linear byte pos in 8KB tile
        ldst[jj] = wave * 2048 + jj * 1024;
        int rk = p >> 8, cbs = (p & 255) ^ ((rk & 7) << 4);
        ksrc[jj] = Kb + ((size_t)(b * 2048 + rk) << 10) + h * 128 + (cbs >> 1);
        int dv = p >> 6, kbs = (p & 63) ^ ((dv & 3) << 4);
        vsrc[jj] = Vtb + (((size_t)(bh * 128 + dv)) << 11) + (kbs >> 1);
    }
    auto stage = [&](int ks0, int buf) {
        char* kb = (char*)Ks[buf];
        char* vb = (char*)Vs[buf];
#pragma unroll
        for (int jj = 0; jj < 2; ++jj) {
            gload16(ksrc[jj] + ((size_t)ks0 << 10), kb + ldst[jj]);
            gload16(vsrc[jj] + ks0, vb + ldst[jj]);
        }
    };

    f32x4 oacc[8];
#pragma unroll
    for (int nf = 0; nf < 8; ++nf) oacc[nf] = f32x4{0.f, 0.f, 0.f, 0.f};
    float mrun = MINIT, lrun = 0.f;
    const float SC = -0.12751741566723328f;  // -log2(e)/sqrt(128)

    const int j0 = half ? (qt + 1) : 0;
    const int j1 = j0 + qt + 1;

    stage(j0 << 5, 0);
    for (int j = j0; j < j1; ++j) {
        const int cur = (j - j0) & 1;
        asm volatile("s_waitcnt vmcnt(0)" ::: "memory");  // tile j landed (mine)
        FULL_BARRIER();                                    // ...and everyone's
        if (j + 1 < j1) stage((j + 1) << 5, cur ^ 1);     // flies under compute

        // QK^T (swapped): sf[mf] reg r = score[k = j*32 + mf*16 + hi*4 + r][q=lo]
        f32x4 sf[2];
        __builtin_amdgcn_s_setprio(1);
#pragma unroll
        for (int mf = 0; mf < 2; ++mf) {
            f32x4 s = {0.f, 0.f, 0.f, 0.f};
            int kr = mf * 16 + lo;
            const char* rowp = (const char*)Ks[cur] + kr * 256;
            int swz = (kr & 7) << 4;
#pragma unroll
            for (int c = 0; c < 4; ++c) {
                s16x8 kf = *(const s16x8*)(rowp + ((c * 64 + hi * 16) ^ swz));
                s = __builtin_amdgcn_mfma_f32_16x16x32_bf16(kf, qf[c], s, 0, 0, 0);
            }
            sf[mf] = s;
        }
        __builtin_amdgcn_s_setprio(0);

        const bool diag = (j >= 2 * qt);
        float p[2][4];
        float pm = MASKV;
#pragma unroll
        for (int mf = 0; mf < 2; ++mf)
#pragma unroll
            for (int r = 0; r < 4; ++r) {
                float sv = sf[mf][r] * SC;
                if (diag) {
                    int kg = j * 32 + mf * 16 + (hi << 2) + r;
                    if (kg > qrow) sv = MASKV;
                }
                p[mf][r] = sv;
                pm = fmaxf(pm, sv);
            }
        pm = fmaxf(pm, __shfl_xor(pm, 16));
        pm = fmaxf(pm, __shfl_xor(pm, 32));

        // defer-rescale: skip O-rescale when max didn't grow
        const bool grow = !__all(pm <= mrun);
        float mnew = mrun;
        if (grow) {
            mnew = fmaxf(mrun, pm);
            float corr = exp2f(mrun - mnew);
            lrun *= corr;
            float cr[4];
#pragma unroll
            for (int r = 0; r < 4; ++r) cr[r] = __shfl(corr, (hi << 2) + r);
#pragma unroll
            for (int nf = 0; nf < 8; ++nf)
#pragma unroll
                for (int r = 0; r < 4; ++r) oacc[nf][r] *= cr[r];
            mrun = mnew;
        }

        float psum = 0.f;
        float p2[2][4];
#pragma unroll
        for (int mf = 0; mf < 2; ++mf)
#pragma unroll
            for (int r = 0; r < 4; ++r) {
                float e = exp2f(p[mf][r] - mnew);
                p2[mf][r] = e;
                psum += e;
            }
        psum += __shfl_xor(psum, 16);
        psum += __shfl_xor(psum, 32);
        lrun += psum;

        // pack P as PV A-operand via v_cvt_pk_bf16_f32 (RNE); k-bijection
        // slot i -> k = hi*4 + (i&3) + 16*(i>>2)
        unsigned pw0, pw1, pw2, pw3;
        asm("v_cvt_pk_bf16_f32 %0, %1, %2" : "=v"(pw0) : "v"(p2[0][0]), "v"(p2[0][1]));
        asm("v_cvt_pk_bf16_f32 %0, %1, %2" : "=v"(pw1) : "v"(p2[0][2]), "v"(p2[0][3]));
        asm("v_cvt_pk_bf16_f32 %0, %1, %2" : "=v"(pw2) : "v"(p2[1][0]), "v"(p2[1][1]));
        asm("v_cvt_pk_bf16_f32 %0, %1, %2" : "=v"(pw3) : "v"(p2[1][2]), "v"(p2[1][3]));
        union { unsigned w[4]; s16x8 v; } pau;
        pau.w[0] = pw0; pau.w[1] = pw1; pau.w[2] = pw2; pau.w[3] = pw3;
        s16x8 pa = pau.v;

        // PV: B-frag slot i reads Vs[d][same k-bijection]
        __builtin_amdgcn_s_setprio(1);
#pragma unroll
        for (int nf = 0; nf < 8; ++nf) {
            int d = nf * 16 + lo;
            const char* vrow = (const char*)Vs[cur] + d * 64;
            int swz = (d & 3) << 4;
            int ob = hi << 3;
            s16x4 vlo = *(const s16x4*)(vrow + (ob ^ swz));
            s16x4 vhi = *(const s16x4*)(vrow + ((ob + 32) ^ swz));
            s16x8 vf = {vlo[0], vlo[1], vlo[2], vlo[3], vhi[0], vhi[1], vhi[2], vhi[3]};
            oacc[nf] = __builtin_amdgcn_mfma_f32_16x16x32_bf16(pa, vf, oacc[nf], 0, 0, 0);
        }
        __builtin_amdgcn_s_setprio(0);
    }

    // epilogue: write unnormalized partial O (bf16) + m,l (f32)
    if (hi == 0) {
        int mi = (half * 16 + bh) * 2048 + qrow;
        Mp[mi] = mrun;
        Lp[mi] = lrun;
    }
    u16* Op = half ? Op1 : Op0;
#pragma unroll
    for (int nf = 0; nf < 8; ++nf) {
        int d = nf * 16 + lo;
#pragma unroll
        for (int r = 0; r < 4; ++r) {
            int q2 = qt * 64 + wave * 16 + (hi << 2) + r;
            Op[((size_t)(b * 2048 + q2) << 10) + h * 128 + d] = f2bf(oacc[nf][r]);
        }
    }
}

// ---------------- combine partials + self-force -> Tb ----------------
__global__ __launch_bounds__(256) void attn_combine(
    const u16* __restrict__ O0, const u16* __restrict__ O1,
    const float* __restrict__ Mp, const float* __restrict__ Lp,
    const u16* __restrict__ Sb, u16* __restrict__ Tb) {
    int i = blockIdx.x * 256 + threadIdx.x;      // 524288 threads, 8 elems each
    int d0 = (i & 15) << 3;
    int row = i >> 4;                            // (b*2048+q)*8 + h
    int h = row & 7;
    int bq = row >> 3;                           // b*2048+q
    int b = bq >> 11, q = bq & 2047;
    int bh = b * 8 + h;
    int mi0 = bh * 2048 + q, mi1 = (16 + bh) * 2048 + q;
    float m0 = Mp[mi0], m1 = Mp[mi1], l0 = Lp[mi0], l1 = Lp[mi1];
    float m = fmaxf(m0, m1);
    float a0 = exp2f(m0 - m), a1 = exp2f(m1 - m);
    float rd = 1.0f / (l0 * a0 + l1 * a1);
    size_t base = ((size_t)bq << 10) + (h << 7) + d0;
    s16x8 o0 = *(const s16x8*)(O0 + base);
    s16x8 o1 = *(const s16x8*)(O1 + base);
    s16x8 sf = *(const s16x8*)(Sb + base);
    u16x8 out;
#pragma unroll
    for (int e = 0; e < 8; ++e)
        out[e] = f2bf((bf2f((u16)o0[e]) * a0 + bf2f((u16)o1[e]) * a1) * rd + bf2f((u16)sf[e]));
    *(u16x8*)(Tb + base) = out;
}

// ---------------- launch ----------------
extern "C" void kernel_launch(void* const* d_in, const int* in_sizes, int n_in,
                              void* d_out, int out_size, void* d_ws, size_t ws_size,
                              hipStream_t stream) {
    const float* x   = (const float*)d_in[0];
    const float* Wk  = (const float*)d_in[1];
    const float* Wv  = (const float*)d_in[2];
    const float* Wsf = (const float*)d_in[3];
    const float* Wo  = (const float*)d_in[4];
    float* out = (float*)d_out;
    char* ws = (char*)d_ws;
    u16* xb  = (u16*)(ws);                       // 8 MB (also O0part / Tb)
    u16* wkb = (u16*)(ws + (8u << 20));
    u16* wvb = (u16*)(ws + (10u << 20));
    u16* wsb = (u16*)(ws + (12u << 20));
    u16* Kb  = (u16*)(ws + (16u << 20));         // 8 MB
    u16* Vtb = (u16*)(ws + (24u << 20));         // 8 MB, [BH][128][2048]
    u16* Sbf = (u16*)(ws + (32u << 20));         // 8 MB
    u16* Tb  = xb;

    u16* wob   = (u16*)(ws + (40u << 20));       // 2 MB
    u16* Op0   = xb;                             // 8 MB (aliases xb/Tb)
    u16* Op1   = (u16*)(ws + (8u << 20));        // 8 MB (over dead wkb/wvb/wsb)
    float* Mp  = (float*)(ws + (42u << 20));     // 256 KB
    float* Lp  = (float*)(ws + (42u << 20) + (256u << 10));

    cast_all<<<8192, 256, 0, stream>>>(x, Wk, Wv, Wsf, Wo, xb, wkb, wvb, wsb, wob);
    gemm_nt<0, 128><<<dim3(8, 32, 3), 256, 0, stream>>>(xb, wkb, wvb, wsb, Kb, Vtb, Sbf, nullptr);
    attn_split<<<dim3(64, 16), 256, 0, stream>>>(Kb, Vtb, Op0, Op1, Mp, Lp);
    attn_combine<<<2048, 256, 0, stream>>>(Op0, Op1, Mp, Lp, Sbf, Tb);
    gemm_nt<1, 64><<<dim3(16, 32, 1), 256, 0, stream>>>(Tb, wob, nullptr, nullptr,
                                                        nullptr, nullptr, nullptr, out);
}

// Round 7
// 227.450 us; speedup vs baseline: 1.0510x; 1.0030x over previous
//
#include <hip/hip_runtime.h>

// EnergyFunction: B=2, S=2048, D=1024, H=8, hd=128
//   K = x@Wk^T, V = x@Wv^T, Sf = x@Wself^T   (bf16 intermediates)
//   att = softmax(-(K K^T)/sqrt(128), causal) @ V
//   out = (att + Sf) @ Wout^T                 (fp32 output)
//
// ws layout (>=43MB):
//   0-8M   xb / O0part / Tb      8-14M wcat [3072x1024] (dead after proj) / O1part(8-16M)
//   16-24M Kb   24-32M Vtb([BH][128][2048])   32-40M Sbf
//   40-42M wob  42M+ Mp(256K), Lp(256K)
//
// R7: 256x128-tile merged projection GEMM (N=3072, 32 MFMA/wave/K-step, 2x
// density) + 2-way LDS swizzle (col16 ^= ((row>>1)&3)<<4, both-sides) for the
// 64B-row ds_read_b128 8-way conflict. Final GEMM same template at 128x128.

typedef unsigned short u16;
typedef short s16x8 __attribute__((ext_vector_type(8)));
typedef short s16x4 __attribute__((ext_vector_type(4)));
typedef unsigned short u16x4 __attribute__((ext_vector_type(4)));
typedef unsigned short u16x8 __attribute__((ext_vector_type(8)));
typedef float f32x4 __attribute__((ext_vector_type(4)));

#define DEV __device__ __forceinline__

DEV u16 f2bf(float f) {
    union { float f; unsigned u; } v; v.f = f;
    return (u16)((v.u + 0x7FFFu + ((v.u >> 16) & 1u)) >> 16);
}
DEV float bf2f(u16 h) {
    union { unsigned u; float f; } v; v.u = ((unsigned)h) << 16;
    return v.f;
}
DEV void gload16(const void* g, void* l) {
    __builtin_amdgcn_global_load_lds(
        (const __attribute__((address_space(1))) void*)g,
        (__attribute__((address_space(3))) void*)l, 16, 0, 0);
}

#define FULL_BARRIER()                          \
    do {                                        \
        __builtin_amdgcn_sched_barrier(0);      \
        __builtin_amdgcn_s_barrier();           \
        __builtin_amdgcn_sched_barrier(0);      \
    } while (0)

// ---------------- cast fp32 -> bf16 (x + 4 weights fused) ----------------
__global__ __launch_bounds__(256) void cast_all(
    const float* __restrict__ x, const float* __restrict__ wk,
    const float* __restrict__ wv, const float* __restrict__ wsf,
    const float* __restrict__ wo,
    u16* __restrict__ xb, u16* __restrict__ wkb, u16* __restrict__ wvb,
    u16* __restrict__ wsb, u16* __restrict__ wob) {
    int i = blockIdx.x * 256 + threadIdx.x;            // float4 index
    const int NX = (2 * 2048 * 1024) / 4;              // 1048576
    const int NW = (1024 * 1024) / 4;                  // 262144
    const float* src; u16* dst; int off;
    if (i < NX)              { src = x;   dst = xb;  off = i; }
    else if (i < NX + NW)    { src = wk;  dst = wkb; off = i - NX; }
    else if (i < NX + 2*NW)  { src = wv;  dst = wvb; off = i - NX - NW; }
    else if (i < NX + 3*NW)  { src = wsf; dst = wsb; off = i - NX - 2*NW; }
    else                     { src = wo;  dst = wob; off = i - NX - 3*NW; }
    float4 v = ((const float4*)src)[off];
    u16x4 o = { f2bf(v.x), f2bf(v.y), f2bf(v.z), f2bf(v.w) };
    ((u16x4*)dst)[off] = o;
}

// ---------------- big-tile NT GEMM ----------------
// MODE 0: 256x128 tile, A=xb[4096x1024], W=wcat[3072x1024]; epilogue routes
//   n-segment 0 -> Kb (bf16), 1 -> Vtb (bf16 per-head transposed), 2 -> Sbf.
// MODE 1: 128x128 tile, A=Tb[4096x1024], W=wob; fp32 out.
// 4 waves, wave owns (BM/4) rows x 128 cols: MF x 8 MFMA per K-step (BK=32).
// LDS swizzle: byte col16 ^= ((row>>1)&3)<<4 within each 64B row; applied on
// BOTH the pre-swizzled global staging source and the frag read (involution).
template <int MODE>
__global__ __launch_bounds__(256, 2) void gemm_big(
    const u16* __restrict__ A, const u16* __restrict__ W,
    u16* __restrict__ Kb, u16* __restrict__ Vtb, u16* __restrict__ Sbf,
    float* __restrict__ Of) {
    constexpr int BM = (MODE == 0) ? 256 : 128;
    constexpr int MF = BM / 64;                 // m-frags per wave (4 or 2)
    __shared__ __align__(16) u16 As[2][BM * 32];
    __shared__ __align__(16) u16 Bs[2][128 * 32];
    const int tid = threadIdx.x, lane = tid & 63, wave = tid >> 6;
    const int hi = lane >> 4, lo = lane & 15;
    const int m0 = blockIdx.y * BM, n0 = blockIdx.x * 128;

    f32x4 acc[MF][8];
#pragma unroll
    for (int i = 0; i < MF; ++i)
#pragma unroll
        for (int j = 0; j < 8; ++j) acc[i][j] = f32x4{0.f, 0.f, 0.f, 0.f};

    // staging: pre-swizzled global source, linear LDS dest (wave-uniform)
    const u16* asrc[MF]; int adst[MF];
#pragma unroll
    for (int q = 0; q < MF; ++q) {
        int p = wave * (MF * 1024) + q * 1024 + lane * 16;
        adst[q] = wave * (MF * 1024) + q * 1024;
        int rw = p >> 6, cb = (p & 63) ^ (((rw >> 1) & 3) << 4);
        asrc[q] = A + ((size_t)(m0 + rw) << 10) + (cb >> 1);
    }
    const u16* bsrc[2]; int bdst[2];
#pragma unroll
    for (int q = 0; q < 2; ++q) {
        int p = wave * 2048 + q * 1024 + lane * 16;
        bdst[q] = wave * 2048 + q * 1024;
        int rw = p >> 6, cb = (p & 63) ^ (((rw >> 1) & 3) << 4);
        bsrc[q] = W + ((size_t)(n0 + rw) << 10) + (cb >> 1);
    }
    auto stage = [&](int k0, int buf) {
#pragma unroll
        for (int q = 0; q < MF; ++q) gload16(asrc[q] + k0, (char*)As[buf] + adst[q]);
#pragma unroll
        for (int q = 0; q < 2; ++q) gload16(bsrc[q] + k0, (char*)Bs[buf] + bdst[q]);
    };

    stage(0, 0);
    const int hb = hi << 4;                     // frag col byte base
    for (int t = 0; t < 32; ++t) {
        const int cur = t & 1;
        asm volatile("s_waitcnt vmcnt(0)" ::: "memory");  // tile t landed (mine)
        FULL_BARRIER();                                    // ...and everyone's
        if (t < 31) stage((t + 1) << 5, cur ^ 1);          // flies under compute
        s16x8 af[MF], bfr[8];
#pragma unroll
        for (int i = 0; i < MF; ++i) {
            int rw = wave * (MF * 16) + i * 16 + lo;
            af[i] = *(const s16x8*)((const char*)As[cur] + rw * 64 + (hb ^ (((rw >> 1) & 3) << 4)));
        }
#pragma unroll
        for (int j = 0; j < 8; ++j) {
            int rw = j * 16 + lo;
            bfr[j] = *(const s16x8*)((const char*)Bs[cur] + rw * 64 + (hb ^ (((rw >> 1) & 3) << 4)));
        }
#pragma unroll
        for (int i = 0; i < MF; ++i)
#pragma unroll
            for (int j = 0; j < 8; ++j)
                acc[i][j] = __builtin_amdgcn_mfma_f32_16x16x32_bf16(af[i], bfr[j], acc[i][j], 0, 0, 0);
    }

    // epilogue: C/D layout col=lane&15 (n), row=(lane>>4)*4+reg (m)
    if (MODE == 1) {
#pragma unroll
        for (int i = 0; i < MF; ++i)
#pragma unroll
            for (int j = 0; j < 8; ++j) {
                int n = n0 + j * 16 + lo;
                int mbase = m0 + wave * (MF * 16) + i * 16 + (hi << 2);
#pragma unroll
                for (int r = 0; r < 4; ++r)
                    Of[((size_t)(mbase + r) << 10) + n] = acc[i][j][r];
            }
    } else {
        const int seg = n0 >> 10, nn0 = n0 & 1023;
        if (seg == 1) {
            // V: write transposed per head: Vt[(b*8+h)*128 + d][s]
#pragma unroll
            for (int i = 0; i < MF; ++i)
#pragma unroll
                for (int j = 0; j < 8; ++j) {
                    int n = nn0 + j * 16 + lo;
                    int h = n >> 7, d = n & 127;
                    int mbase = m0 + wave * (MF * 16) + i * 16 + (hi << 2);
                    int b = mbase >> 11, s = mbase & 2047;
                    u16x4 pk;
#pragma unroll
                    for (int r = 0; r < 4; ++r) pk[r] = f2bf(acc[i][j][r]);
                    *(u16x4*)(Vtb + (((size_t)(b * 8 + h) << 7) + d) * 2048 + s) = pk;
                }
        } else {
            u16* dst = seg ? Sbf : Kb;
#pragma unroll
            for (int i = 0; i < MF; ++i)
#pragma unroll
                for (int j = 0; j < 8; ++j) {
                    int n = nn0 + j * 16 + lo;
                    int mbase = m0 + wave * (MF * 16) + i * 16 + (hi << 2);
#pragma unroll
                    for (int r = 0; r < 4; ++r)
                        dst[((size_t)(mbase + r) << 10) + n] = f2bf(acc[i][j][r]);
                }
        }
    }
}

// ---------------- split-K causal flash attention ----------------
// grid (64, 16): bx -> (q_raw = bx>>1, half = bx&1); qt remapped by bh bit2 so
// co-resident blocks pair to constant total iterations. KVBLK=32, dbuf LDS =
// 32KB -> 4 blocks/CU. Unnormalized O + (m,l) partials; finite sentinels.
#define MINIT (-30000.0f)
#define MASKV (-60000.0f)
__global__ __launch_bounds__(256, 4) void attn_split(
    const u16* __restrict__ Kb, const u16* __restrict__ Vtb,
    u16* __restrict__ Op0, u16* __restrict__ Op1,
    float* __restrict__ Mp, float* __restrict__ Lp) {
    __shared__ __align__(16) u16 Ks[2][32 * 128];   // K tile [k][d], 256B rows, swz (r&7)<<4
    __shared__ __align__(16) u16 Vs[2][128 * 32];   // V^T tile [d][k], 64B rows, swz (d&3)<<4
    const int tid = threadIdx.x, lane = tid & 63, wave = tid >> 6;
    const int q_raw = blockIdx.x >> 1, half = blockIdx.x & 1;
    const int bh = blockIdx.y, b = bh >> 3, h = bh & 7;
    const int qt = ((bh >> 2) & 1) ? q_raw : (31 - q_raw);
    const int hi = lane >> 4, lo = lane & 15;
    const int qrow = qt * 64 + wave * 16 + lo;      // this lane's P-column q

    s16x8 qf[4];
    {
        const u16* qp = Kb + ((size_t)(b * 2048 + qrow) << 10) + h * 128 + (hi << 3);
#pragma unroll
        for (int c = 0; c < 4; ++c) qf[c] = *(const s16x8*)(qp + c * 32);
    }

    // staging: 2 chunks/wave for K (8KB tile) and V (8KB tile)
    const u16* ksrc[2];
    const u16* vsrc[2];
    int ldst[2];
#pragma unroll
    for (int jj = 0; jj < 2; ++jj) {
        int p = wave * 2048 + jj * 1024 + lane * 16;  // linear byte pos in 8KB tile
        ldst[jj] = wave * 2048 + jj * 1024;
        int rk = p >> 8, cbs = (p & 255) ^ ((rk & 7) << 4);
        ksrc[jj] = Kb + ((size_t)(b * 2048 + rk) << 10) + h * 128 + (cbs >> 1);
        int dv = p >> 6, kbs = (p & 63) ^ ((dv & 3) << 4);
        vsrc[jj] = Vtb + (((size_t)(bh * 128 + dv)) << 11) + (kbs >> 1);
    }
    auto stage = [&](int ks0, int buf) {
        char* kb = (char*)Ks[buf];
        char* vb = (char*)Vs[buf];
#pragma unroll
        for (int jj = 0; jj < 2; ++jj) {
            gload16(ksrc[jj] + ((size_t)ks0 << 10), kb + ldst[jj]);
            gload16(vsrc[jj] + ks0, vb + ldst[jj]);
        }
    };

    f32x4 oacc[8];
#pragma unroll
    for (int nf = 0; nf < 8; ++nf) oacc[nf] = f32x4{0.f, 0.f, 0.f, 0.f};
    float mrun = MINIT, lrun = 0.f;
    const float SC = -0.12751741566723328f;  // -log2(e)/sqrt(128)

    const int j0 = half ? (qt + 1) : 0;
    const int j1 = j0 + qt + 1;

    stage(j0 << 5, 0);
    for (int j = j0; j < j1; ++j) {
        const int cur = (j - j0) & 1;
        asm volatile("s_waitcnt vmcnt(0)" ::: "memory");  // tile j landed (mine)
        FULL_BARRIER();                                    // ...and everyone's
        if (j + 1 < j1) stage((j + 1) << 5, cur ^ 1);     // flies under compute

        // QK^T (swapped): sf[mf] reg r = score[k = j*32 + mf*16 + hi*4 + r][q=lo]
        f32x4 sf[2];
        __builtin_amdgcn_s_setprio(1);
#pragma unroll
        for (int mf = 0; mf < 2; ++mf) {
            f32x4 s = {0.f, 0.f, 0.f, 0.f};
            int kr = mf * 16 + lo;
            const char* rowp = (const char*)Ks[cur] + kr * 256;
            int swz = (kr & 7) << 4;
#pragma unroll
            for (int c = 0; c < 4; ++c) {
                s16x8 kf = *(const s16x8*)(rowp + ((c * 64 + hi * 16) ^ swz));
                s = __builtin_amdgcn_mfma_f32_16x16x32_bf16(kf, qf[c], s, 0, 0, 0);
            }
            sf[mf] = s;
        }
        __builtin_amdgcn_s_setprio(0);

        const bool diag = (j >= 2 * qt);
        float p[2][4];
        float pm = MASKV;
#pragma unroll
        for (int mf = 0; mf < 2; ++mf)
#pragma unroll
            for (int r = 0; r < 4; ++r) {
                float sv = sf[mf][r] * SC;
                if (diag) {
                    int kg = j * 32 + mf * 16 + (hi << 2) + r;
                    if (kg > qrow) sv = MASKV;
                }
                p[mf][r] = sv;
                pm = fmaxf(pm, sv);
            }
        pm = fmaxf(pm, __shfl_xor(pm, 16));
        pm = fmaxf(pm, __shfl_xor(pm, 32));

        // defer-rescale: skip O-rescale when max didn't grow
        const bool grow = !__all(pm <= mrun);
        float mnew = mrun;
        if (grow) {
            mnew = fmaxf(mrun, pm);
            float corr = exp2f(mrun - mnew);
            lrun *= corr;
            float cr[4];
#pragma unroll
            for (int r = 0; r < 4; ++r) cr[r] = __shfl(corr, (hi << 2) + r);
#pragma unroll
            for (int nf = 0; nf < 8; ++nf)
#pragma unroll
                for (int r = 0; r < 4; ++r) oacc[nf][r] *= cr[r];
            mrun = mnew;
        }

        float psum = 0.f;
        float p2[2][4];
#pragma unroll
        for (int mf = 0; mf < 2; ++mf)
#pragma unroll
            for (int r = 0; r < 4; ++r) {
                float e = exp2f(p[mf][r] - mnew);
                p2[mf][r] = e;
                psum += e;
            }
        psum += __shfl_xor(psum, 16);
        psum += __shfl_xor(psum, 32);
        lrun += psum;

        // pack P as PV A-operand via v_cvt_pk_bf16_f32 (RNE); k-bijection
        // slot i -> k = hi*4 + (i&3) + 16*(i>>2)
        unsigned pw0, pw1, pw2, pw3;
        asm("v_cvt_pk_bf16_f32 %0, %1, %2" : "=v"(pw0) : "v"(p2[0][0]), "v"(p2[0][1]));
        asm("v_cvt_pk_bf16_f32 %0, %1, %2" : "=v"(pw1) : "v"(p2[0][2]), "v"(p2[0][3]));
        asm("v_cvt_pk_bf16_f32 %0, %1, %2" : "=v"(pw2) : "v"(p2[1][0]), "v"(p2[1][1]));
        asm("v_cvt_pk_bf16_f32 %0, %1, %2" : "=v"(pw3) : "v"(p2[1][2]), "v"(p2[1][3]));
        union { unsigned w[4]; s16x8 v; } pau;
        pau.w[0] = pw0; pau.w[1] = pw1; pau.w[2] = pw2; pau.w[3] = pw3;
        s16x8 pa = pau.v;

        // PV: B-frag slot i reads Vs[d][same k-bijection]
        __builtin_amdgcn_s_setprio(1);
#pragma unroll
        for (int nf = 0; nf < 8; ++nf) {
            int d = nf * 16 + lo;
            const char* vrow = (const char*)Vs[cur] + d * 64;
            int swz = (d & 3) << 4;
            int ob = hi << 3;
            s16x4 vlo = *(const s16x4*)(vrow + (ob ^ swz));
            s16x4 vhi = *(const s16x4*)(vrow + ((ob + 32) ^ swz));
            s16x8 vf = {vlo[0], vlo[1], vlo[2], vlo[3], vhi[0], vhi[1], vhi[2], vhi[3]};
            oacc[nf] = __builtin_amdgcn_mfma_f32_16x16x32_bf16(pa, vf, oacc[nf], 0, 0, 0);
        }
        __builtin_amdgcn_s_setprio(0);
    }

    // epilogue: write unnormalized partial O (bf16) + m,l (f32)
    if (hi == 0) {
        int mi = (half * 16 + bh) * 2048 + qrow;
        Mp[mi] = mrun;
        Lp[mi] = lrun;
    }
    u16* Op = half ? Op1 : Op0;
#pragma unroll
    for (int nf = 0; nf < 8; ++nf) {
        int d = nf * 16 + lo;
#pragma unroll
        for (int r = 0; r < 4; ++r) {
            int q2 = qt * 64 + wave * 16 + (hi << 2) + r;
            Op[((size_t)(b * 2048 + q2) << 10) + h * 128 + d] = f2bf(oacc[nf][r]);
        }
    }
}

// ---------------- combine partials + self-force -> Tb ----------------
__global__ __launch_bounds__(256) void attn_combine(
    const u16* __restrict__ O0, const u16* __restrict__ O1,
    const float* __restrict__ Mp, const float* __restrict__ Lp,
    const u16* __restrict__ Sb, u16* __restrict__ Tb) {
    int i = blockIdx.x * 256 + threadIdx.x;      // 524288 threads, 8 elems each
    int d0 = (i & 15) << 3;
    int row = i >> 4;                            // (b*2048+q)*8 + h
    int h = row & 7;
    int bq = row >> 3;                           // b*2048+q
    int b = bq >> 11, q = bq & 2047;
    int bh = b * 8 + h;
    int mi0 = bh * 2048 + q, mi1 = (16 + bh) * 2048 + q;
    float m0 = Mp[mi0], m1 = Mp[mi1], l0 = Lp[mi0], l1 = Lp[mi1];
    float m = fmaxf(m0, m1);
    float a0 = exp2f(m0 - m), a1 = exp2f(m1 - m);
    float rd = 1.0f / (l0 * a0 + l1 * a1);
    size_t base = ((size_t)bq << 10) + (h << 7) + d0;
    s16x8 o0 = *(const s16x8*)(O0 + base);
    s16x8 o1 = *(const s16x8*)(O1 + base);
    s16x8 sf = *(const s16x8*)(Sb + base);
    u16x8 out;
#pragma unroll
    for (int e = 0; e < 8; ++e)
        out[e] = f2bf((bf2f((u16)o0[e]) * a0 + bf2f((u16)o1[e]) * a1) * rd + bf2f((u16)sf[e]));
    *(u16x8*)(Tb + base) = out;
}

// ---------------- launch ----------------
extern "C" void kernel_launch(void* const* d_in, const int* in_sizes, int n_in,
                              void* d_out, int out_size, void* d_ws, size_t ws_size,
                              hipStream_t stream) {
    const float* x   = (const float*)d_in[0];
    const float* Wk  = (const float*)d_in[1];
    const float* Wv  = (const float*)d_in[2];
    const float* Wsf = (const float*)d_in[3];
    const float* Wo  = (const float*)d_in[4];
    float* out = (float*)d_out;
    char* ws = (char*)d_ws;
    u16* xb   = (u16*)(ws);                      // 8 MB (also O0part / Tb)
    u16* wcat = (u16*)(ws + (8u << 20));         // 6 MB [3072x1024] (dead after proj)
    u16* Kb   = (u16*)(ws + (16u << 20));        // 8 MB
    u16* Vtb  = (u16*)(ws + (24u << 20));        // 8 MB, [BH][128][2048]
    u16* Sbf  = (u16*)(ws + (32u << 20));        // 8 MB
    u16* Tb   = xb;

    u16* wob   = (u16*)(ws + (40u << 20));       // 2 MB
    u16* Op0   = xb;                             // 8 MB (aliases xb/Tb)
    u16* Op1   = (u16*)(ws + (8u << 20));        // 8 MB (over dead wcat)
    float* Mp  = (float*)(ws + (42u << 20));     // 256 KB
    float* Lp  = (float*)(ws + (42u << 20) + (256u << 10));

    cast_all<<<8192, 256, 0, stream>>>(x, Wk, Wv, Wsf, Wo,
                                       xb, wcat, wcat + (1u << 20), wcat + (2u << 20), wob);
    gemm_big<0><<<dim3(24, 16), 256, 0, stream>>>(xb, wcat, Kb, Vtb, Sbf, nullptr);
    attn_split<<<dim3(64, 16), 256, 0, stream>>>(Kb, Vtb, Op0, Op1, Mp, Lp);
    attn_combine<<<2048, 256, 0, stream>>>(Op0, Op1, Mp, Lp, Sbf, Tb);
    gemm_big<1><<<dim3(8, 32), 256, 0, stream>>>(Tb, wob, nullptr, nullptr, nullptr, out);
}

// Round 8
// 223.085 us; speedup vs baseline: 1.0715x; 1.0196x over previous
//
#include <hip/hip_runtime.h>

// EnergyFunction: B=2, S=2048, D=1024, H=8, hd=128
//   K = x@Wk^T, V = x@Wv^T, Sf = x@Wself^T   (bf16 intermediates)
//   att = softmax(-(K K^T)/sqrt(128), causal) @ V
//   out = (att + Sf) @ Wout^T                 (fp32 output)
//
// ws layout (>=43MB):
//   0-8M   xb / O0part / Tb      8-14M wcat [3072x1024] (dead after proj) / O1part(8-16M)
//   16-24M Kb   24-32M Vtb([BH][128][2048])   32-40M Sbf
//   40-42M wob  42M+ Mp(256K), Lp(256K)
//
// R8: projection GEMM = 8-phase 256x256 template (T3+T4): BK=64, 8 waves,
// 128KB dbuf LDS, counted vmcnt(8) twice per 2-K-tile iteration (never 0
// mid-loop), per-phase barrier/lgkm/setprio MFMA clusters, cross-row XOR
// swizzle (chunk ^= row&7) with pre-swizzled global source.

typedef unsigned short u16;
typedef short s16x8 __attribute__((ext_vector_type(8)));
typedef short s16x4 __attribute__((ext_vector_type(4)));
typedef unsigned short u16x4 __attribute__((ext_vector_type(4)));
typedef unsigned short u16x8 __attribute__((ext_vector_type(8)));
typedef float f32x4 __attribute__((ext_vector_type(4)));

#define DEV __device__ __forceinline__

DEV u16 f2bf(float f) {
    union { float f; unsigned u; } v; v.f = f;
    return (u16)((v.u + 0x7FFFu + ((v.u >> 16) & 1u)) >> 16);
}
DEV float bf2f(u16 h) {
    union { unsigned u; float f; } v; v.u = ((unsigned)h) << 16;
    return v.f;
}
DEV void gload16(const void* g, void* l) {
    __builtin_amdgcn_global_load_lds(
        (const __attribute__((address_space(1))) void*)g,
        (__attribute__((address_space(3))) void*)l, 16, 0, 0);
}

#define FULL_BARRIER()                          \
    do {                                        \
        __builtin_amdgcn_sched_barrier(0);      \
        __builtin_amdgcn_s_barrier();           \
        __builtin_amdgcn_sched_barrier(0);      \
    } while (0)

#define LGKM0_FENCE()                                        \
    do {                                                     \
        asm volatile("s_waitcnt lgkmcnt(0)" ::: "memory");   \
        __builtin_amdgcn_sched_barrier(0);                   \
    } while (0)

// ---------------- cast fp32 -> bf16 (x + 4 weights fused) ----------------
__global__ __launch_bounds__(256) void cast_all(
    const float* __restrict__ x, const float* __restrict__ wk,
    const float* __restrict__ wv, const float* __restrict__ wsf,
    const float* __restrict__ wo,
    u16* __restrict__ xb, u16* __restrict__ wkb, u16* __restrict__ wvb,
    u16* __restrict__ wsb, u16* __restrict__ wob) {
    int i = blockIdx.x * 256 + threadIdx.x;            // float4 index
    const int NX = (2 * 2048 * 1024) / 4;              // 1048576
    const int NW = (1024 * 1024) / 4;                  // 262144
    const float* src; u16* dst; int off;
    if (i < NX)              { src = x;   dst = xb;  off = i; }
    else if (i < NX + NW)    { src = wk;  dst = wkb; off = i - NX; }
    else if (i < NX + 2*NW)  { src = wv;  dst = wvb; off = i - NX - NW; }
    else if (i < NX + 3*NW)  { src = wsf; dst = wsb; off = i - NX - 2*NW; }
    else                     { src = wo;  dst = wob; off = i - NX - 3*NW; }
    float4 v = ((const float4*)src)[off];
    u16x4 o = { f2bf(v.x), f2bf(v.y), f2bf(v.z), f2bf(v.w) };
    ((u16x4*)dst)[off] = o;
}

// ---------------- 8-phase 256x256 projection GEMM ----------------
// C[m][n] = sum_k A[m][k]*W[n][k]; A=xb[4096x1024], W=wcat[3072x1024].
// Epilogue routes n-segment: 0 -> Kb, 1 -> Vtb (per-head transposed), 2 -> Sbf.
// 8 waves (2M x 4N), per-wave 128x64 out = acc[8][4]. K-tile BK=64, dbuf.
// LDS rows 128B; swizzle: 16B-chunk c' = c ^ (row&7) (rows -> 8 bank groups,
// 2-way = free). Staging: linear LDS dest + inverse-swizzled global source.
// Waits: vmcnt(8) before the end-barrier of P4 and P8 only (counted, T4).
__global__ __launch_bounds__(512, 2) void gemm8_proj(
    const u16* __restrict__ A, const u16* __restrict__ W,
    u16* __restrict__ Kb, u16* __restrict__ Vtb, u16* __restrict__ Sbf) {
    __shared__ __align__(16) u16 As[2][256 * 64];   // 64 KB
    __shared__ __align__(16) u16 Bs[2][256 * 64];   // 64 KB
    const int tid = threadIdx.x, lane = tid & 63, wave = tid >> 6;
    const int hi = lane >> 4, lo = lane & 15;
    const int wr = wave >> 2, wc = wave & 3;        // 2 x 4 wave grid

    // XCD-bijective block swizzle (nwg=192, 192%8==0)
    const int nwg = gridDim.x, cpx = nwg >> 3, o = blockIdx.x;
    const int wg = (o & 7) * cpx + (o >> 3);
    const int bm = wg & 15, bn = wg >> 4;           // 16 x 12 tiles
    const int m0 = bm << 8, n0 = bn << 8;

    f32x4 acc[8][4];
#pragma unroll
    for (int i = 0; i < 8; ++i)
#pragma unroll
        for (int j = 0; j < 4; ++j) acc[i][j] = f32x4{0.f, 0.f, 0.f, 0.f};

    // staging: half hh in {0:A-h0, 1:A-h1, 2:B-h0, 3:B-h1}; 2 loads/thread/half
    const u16* sp[8];
    int ldst[8];
#pragma unroll
    for (int hh = 0; hh < 4; ++hh)
#pragma unroll
        for (int q = 0; q < 2; ++q) {
            int seg = wave * 2 + q;
            int p = seg * 1024 + lane * 16;         // byte within 16KB half
            int lr = p >> 7, c = (p >> 4) & 7;
            int r = ((hh & 1) << 7) + lr;           // row within 256-row tile
            int cl = c ^ (r & 7);                   // inverse swizzle (involution)
            const u16* base = (hh < 2) ? (A + ((size_t)(m0 + r) << 10))
                                       : (W + ((size_t)(n0 + r) << 10));
            sp[hh * 2 + q] = base + (cl << 3);
            ldst[hh * 2 + q] = ((hh & 1) << 14) + seg * 1024;
        }

    auto stageH = [&](int hh, int k0, int buf) {    // one half-tile (2 loads)
        char* dst = (hh < 2) ? (char*)As[buf] : (char*)Bs[buf];
#pragma unroll
        for (int q = 0; q < 2; ++q)
            gload16(sp[hh * 2 + q] + k0, dst + ldst[hh * 2 + q]);
    };
    auto readA = [&](int buf, int i, int kk) -> s16x8 {
        int r = (wr << 7) + (i << 4) + lo;
        int cl = (kk << 2) + hi;
        return *(const s16x8*)((const char*)As[buf] + r * 128 + ((cl ^ (r & 7)) << 4));
    };
    auto readB = [&](int buf, int j, int kk) -> s16x8 {
        int r = (wc << 6) + (j << 4) + lo;
        int cl = (kk << 2) + hi;
        return *(const s16x8*)((const char*)Bs[buf] + r * 128 + ((cl ^ (r & 7)) << 4));
    };

    // one K-tile = 4 phases; stages push tile t+2's halves into regions of
    // this buffer whose reads completed in the previous phase.
    auto ktile = [&](int buf, int k0, int sk0, bool ds, bool last) {
        s16x8 alo[4], ahi[4], b0[4], b1[4];
        // P1: read A[i0-3][kk0,1] + B[j][kk0]
#pragma unroll
        for (int i = 0; i < 4; ++i) { alo[i] = readA(buf, i, 0); ahi[i] = readA(buf, i, 1); }
#pragma unroll
        for (int j = 0; j < 4; ++j) b0[j] = readB(buf, j, 0);
        FULL_BARRIER();
        LGKM0_FENCE();
        __builtin_amdgcn_s_setprio(1);
#pragma unroll
        for (int i = 0; i < 4; ++i)
#pragma unroll
            for (int j = 0; j < 4; ++j)
                acc[i][j] = __builtin_amdgcn_mfma_f32_16x16x32_bf16(alo[i], b0[j], acc[i][j], 0, 0, 0);
        __builtin_amdgcn_s_setprio(0);
        FULL_BARRIER();
        // P2: read B[j][kk1]
#pragma unroll
        for (int j = 0; j < 4; ++j) b1[j] = readB(buf, j, 1);
        FULL_BARRIER();
        LGKM0_FENCE();
        __builtin_amdgcn_s_setprio(1);
#pragma unroll
        for (int i = 0; i < 4; ++i)
#pragma unroll
            for (int j = 0; j < 4; ++j)
                acc[i][j] = __builtin_amdgcn_mfma_f32_16x16x32_bf16(ahi[i], b1[j], acc[i][j], 0, 0, 0);
        __builtin_amdgcn_s_setprio(0);
        FULL_BARRIER();
        // P3: read A[i4-7][kk0,1]; stage B-h0 of tile t+2 (B reads done at P2)
#pragma unroll
        for (int i = 0; i < 4; ++i) { alo[i] = readA(buf, i + 4, 0); ahi[i] = readA(buf, i + 4, 1); }
        if (ds) stageH(2, sk0, buf);
        FULL_BARRIER();
        LGKM0_FENCE();
        __builtin_amdgcn_s_setprio(1);
#pragma unroll
        for (int i = 0; i < 4; ++i)
#pragma unroll
            for (int j = 0; j < 4; ++j)
                acc[i + 4][j] = __builtin_amdgcn_mfma_f32_16x16x32_bf16(alo[i], b0[j], acc[i + 4][j], 0, 0, 0);
        __builtin_amdgcn_s_setprio(0);
        FULL_BARRIER();
        // P4: stage B-h1, A-h0, A-h1 (A reads done at P3); counted wait
        if (ds) { stageH(3, sk0, buf); stageH(0, sk0, buf); stageH(1, sk0, buf); }
        FULL_BARRIER();
        LGKM0_FENCE();
        __builtin_amdgcn_s_setprio(1);
#pragma unroll
        for (int i = 0; i < 4; ++i)
#pragma unroll
            for (int j = 0; j < 4; ++j)
                acc[i + 4][j] = __builtin_amdgcn_mfma_f32_16x16x32_bf16(ahi[i], b1[j], acc[i + 4][j], 0, 0, 0);
        __builtin_amdgcn_s_setprio(0);
        if (!last) asm volatile("s_waitcnt vmcnt(8)" ::: "memory");
        else       asm volatile("s_waitcnt vmcnt(0)" ::: "memory");
        FULL_BARRIER();   // after this, the tile gated by the wait is visible
    };

    // prologue: stage tiles 0 (buf0) and 1 (buf1)
#pragma unroll
    for (int hh = 0; hh < 4; ++hh) stageH(hh, 0, 0);
#pragma unroll
    for (int hh = 0; hh < 4; ++hh) stageH(hh, 64, 1);
    asm volatile("s_waitcnt vmcnt(8)" ::: "memory");    // tile 0 landed (mine)
    FULL_BARRIER();                                      // ...and everyone's

    for (int it = 0; it < 8; ++it) {
        const bool ds = it < 7, last = it == 7;
        ktile(0, (2 * it) * 64,     (2 * it + 2) * 64, ds, last);
        ktile(1, (2 * it + 1) * 64, (2 * it + 3) * 64, ds, last);
    }

    // epilogue: C/D layout col=lane&15 (n), row=(lane>>4)*4+reg (m)
    const int seg = n0 >> 10, nn0 = (n0 & 1023) + wc * 64;
    const int mb = m0 + wr * 128;
    if (seg == 1) {
        // V: write transposed per head: Vt[(b*8+h)*128 + d][s]
#pragma unroll
        for (int i = 0; i < 8; ++i)
#pragma unroll
            for (int j = 0; j < 4; ++j) {
                int n = nn0 + j * 16 + lo;
                int h = n >> 7, d = n & 127;
                int mbase = mb + i * 16 + (hi << 2);
                int b = mbase >> 11, s = mbase & 2047;
                u16x4 pk;
#pragma unroll
                for (int r = 0; r < 4; ++r) pk[r] = f2bf(acc[i][j][r]);
                *(u16x4*)(Vtb + (((size_t)(b * 8 + h) << 7) + d) * 2048 + s) = pk;
            }
    } else {
        u16* dst = seg ? Sbf : Kb;
#pragma unroll
        for (int i = 0; i < 8; ++i)
#pragma unroll
            for (int j = 0; j < 4; ++j) {
                int n = nn0 + j * 16 + lo;
                int mbase = mb + i * 16 + (hi << 2);
#pragma unroll
                for (int r = 0; r < 4; ++r)
                    dst[((size_t)(mbase + r) << 10) + n] = f2bf(acc[i][j][r]);
            }
    }
}

// ---------------- output GEMM (128x128, 2-phase, unchanged R7) ----------------
__global__ __launch_bounds__(256, 2) void gemm_out(
    const u16* __restrict__ A, const u16* __restrict__ W,
    float* __restrict__ Of) {
    __shared__ __align__(16) u16 As[2][128 * 32];
    __shared__ __align__(16) u16 Bs[2][128 * 32];
    const int tid = threadIdx.x, lane = tid & 63, wave = tid >> 6;
    const int hi = lane >> 4, lo = lane & 15;
    const int m0 = blockIdx.y * 128, n0 = blockIdx.x * 128;

    f32x4 acc[2][8];
#pragma unroll
    for (int i = 0; i < 2; ++i)
#pragma unroll
        for (int j = 0; j < 8; ++j) acc[i][j] = f32x4{0.f, 0.f, 0.f, 0.f};

    const u16* asrc[2]; int adst[2];
#pragma unroll
    for (int q = 0; q < 2; ++q) {
        int p = wave * 2048 + q * 1024 + lane * 16;
        adst[q] = wave * 2048 + q * 1024;
        int rw = p >> 6, cb = (p & 63) ^ (((rw >> 1) & 3) << 4);
        asrc[q] = A + ((size_t)(m0 + rw) << 10) + (cb >> 1);
    }
    const u16* bsrc[2]; int bdst[2];
#pragma unroll
    for (int q = 0; q < 2; ++q) {
        int p = wave * 2048 + q * 1024 + lane * 16;
        bdst[q] = wave * 2048 + q * 1024;
        int rw = p >> 6, cb = (p & 63) ^ (((rw >> 1) & 3) << 4);
        bsrc[q] = W + ((size_t)(n0 + rw) << 10) + (cb >> 1);
    }
    auto stage = [&](int k0, int buf) {
#pragma unroll
        for (int q = 0; q < 2; ++q) gload16(asrc[q] + k0, (char*)As[buf] + adst[q]);
#pragma unroll
        for (int q = 0; q < 2; ++q) gload16(bsrc[q] + k0, (char*)Bs[buf] + bdst[q]);
    };

    stage(0, 0);
    const int hb = hi << 4;
    for (int t = 0; t < 32; ++t) {
        const int cur = t & 1;
        asm volatile("s_waitcnt vmcnt(0)" ::: "memory");
        FULL_BARRIER();
        if (t < 31) stage((t + 1) << 5, cur ^ 1);
        s16x8 af[2], bfr[8];
#pragma unroll
        for (int i = 0; i < 2; ++i) {
            int rw = wave * 32 + i * 16 + lo;
            af[i] = *(const s16x8*)((const char*)As[cur] + rw * 64 + (hb ^ (((rw >> 1) & 3) << 4)));
        }
#pragma unroll
        for (int j = 0; j < 8; ++j) {
            int rw = j * 16 + lo;
            bfr[j] = *(const s16x8*)((const char*)Bs[cur] + rw * 64 + (hb ^ (((rw >> 1) & 3) << 4)));
        }
#pragma unroll
        for (int i = 0; i < 2; ++i)
#pragma unroll
            for (int j = 0; j < 8; ++j)
                acc[i][j] = __builtin_amdgcn_mfma_f32_16x16x32_bf16(af[i], bfr[j], acc[i][j], 0, 0, 0);
    }
#pragma unroll
    for (int i = 0; i < 2; ++i)
#pragma unroll
        for (int j = 0; j < 8; ++j) {
            int n = n0 + j * 16 + lo;
            int mbase = m0 + wave * 32 + i * 16 + (hi << 2);
#pragma unroll
            for (int r = 0; r < 4; ++r)
                Of[((size_t)(mbase + r) << 10) + n] = acc[i][j][r];
        }
}

// ---------------- split-K causal flash attention (unchanged) ----------------
#define MINIT (-30000.0f)
#define MASKV (-60000.0f)
__global__ __launch_bounds__(256, 4) void attn_split(
    const u16* __restrict__ Kb, const u16* __restrict__ Vtb,
    u16* __restrict__ Op0, u16* __restrict__ Op1,
    float* __restrict__ Mp, float* __restrict__ Lp) {
    __shared__ __align__(16) u16 Ks[2][32 * 128];
    __shared__ __align__(16) u16 Vs[2][128 * 32];
    const int tid = threadIdx.x, lane = tid & 63, wave = tid >> 6;
    const int q_raw = blockIdx.x >> 1, half = blockIdx.x & 1;
    const int bh = blockIdx.y, b = bh >> 3, h = bh & 7;
    const int qt = ((bh >> 2) & 1) ? q_raw : (31 - q_raw);
    const int hi = lane >> 4, lo = lane & 15;
    const int qrow = qt * 64 + wave * 16 + lo;

    s16x8 qf[4];
    {
        const u16* qp = Kb + ((size_t)(b * 2048 + qrow) << 10) + h * 128 + (hi << 3);
#pragma unroll
        for (int c = 0; c < 4; ++c) qf[c] = *(const s16x8*)(qp + c * 32);
    }
    const u16* ksrc[2];
    const u16* vsrc[2];
    int ldst[2];
#pragma unroll
    for (int jj = 0; jj < 2; ++jj) {
        int p = wave * 2048 + jj * 1024 + lane * 16;
        ldst[jj] = wave * 2048 + jj * 1024;
        int rk = p >> 8, cbs = (p & 255) ^ ((rk & 7) << 4);
        ksrc[jj] = Kb + ((size_t)(b * 2048 + rk) << 10) + h * 128 + (cbs >> 1);
        int dv = p >> 6, kbs = (p & 63) ^ ((dv & 3) << 4);
        vsrc[jj] = Vtb + (((size_t)(bh * 128 + dv)) << 11) + (kbs >> 1);
    }
    auto stage = [&](int ks0, int buf) {
        char* kb = (char*)Ks[buf];
        char* vb = (char*)Vs[buf];
#pragma unroll
        for (int jj = 0; jj < 2; ++jj) {
            gload16(ksrc[jj] + ((size_t)ks0 << 10), kb + ldst[jj]);
            gload16(vsrc[jj] + ks0, vb + ldst[jj]);
        }
    };

    f32x4 oacc[8];
#pragma unroll
    for (int nf = 0; nf < 8; ++nf) oacc[nf] = f32x4{0.f, 0.f, 0.f, 0.f};
    float mrun = MINIT, lrun = 0.f;
    const float SC = -0.12751741566723328f;

    const int j0 = half ? (qt + 1) : 0;
    const int j1 = j0 + qt + 1;

    stage(j0 << 5, 0);
    for (int j = j0; j < j1; ++j) {
        const int cur = (j - j0) & 1;
        asm volatile("s_waitcnt vmcnt(0)" ::: "memory");
        FULL_BARRIER();
        if (j + 1 < j1) stage((j + 1) << 5, cur ^ 1);

        f32x4 sf[2];
        __builtin_amdgcn_s_setprio(1);
#pragma unroll
        for (int mf = 0; mf < 2; ++mf) {
            f32x4 s = {0.f, 0.f, 0.f, 0.f};
            int kr = mf * 16 + lo;
            const char* rowp = (const char*)Ks[cur] + kr * 256;
            int swz = (kr & 7) << 4;
#pragma unroll
            for (int c = 0; c < 4; ++c) {
                s16x8 kf = *(const s16x8*)(rowp + ((c * 64 + hi * 16) ^ swz));
                s = __builtin_amdgcn_mfma_f32_16x16x32_bf16(kf, qf[c], s, 0, 0, 0);
            }
            sf[mf] = s;
        }
        __builtin_amdgcn_s_setprio(0);

        const bool diag = (j >= 2 * qt);
        float p[2][4];
        float pm = MASKV;
#pragma unroll
        for (int mf = 0; mf < 2; ++mf)
#pragma unroll
            for (int r = 0; r < 4; ++r) {
                float sv = sf[mf][r] * SC;
                if (diag) {
                    int kg = j * 32 + mf * 16 + (hi << 2) + r;
                    if (kg > qrow) sv = MASKV;
                }
                p[mf][r] = sv;
                pm = fmaxf(pm, sv);
            }
        pm = fmaxf(pm, __shfl_xor(pm, 16));
        pm = fmaxf(pm, __shfl_xor(pm, 32));

        const bool grow = !__all(pm <= mrun);
        float mnew = mrun;
        if (grow) {
            mnew = fmaxf(mrun, pm);
            float corr = exp2f(mrun - mnew);
            lrun *= corr;
            float cr[4];
#pragma unroll
            for (int r = 0; r < 4; ++r) cr[r] = __shfl(corr, (hi << 2) + r);
#pragma unroll
            for (int nf = 0; nf < 8; ++nf)
#pragma unroll
                for (int r = 0; r < 4; ++r) oacc[nf][r] *= cr[r];
            mrun = mnew;
        }

        float psum = 0.f;
        float p2[2][4];
#pragma unroll
        for (int mf = 0; mf < 2; ++mf)
#pragma unroll
            for (int r = 0; r < 4; ++r) {
                float e = exp2f(p[mf][r] - mnew);
                p2[mf][r] = e;
                psum += e;
            }
        psum += __shfl_xor(psum, 16);
        psum += __shfl_xor(psum, 32);
        lrun += psum;

        unsigned pw0, pw1, pw2, pw3;
        asm("v_cvt_pk_bf16_f32 %0, %1, %2" : "=v"(pw0) : "v"(p2[0][0]), "v"(p2[0][1]));
        asm("v_cvt_pk_bf16_f32 %0, %1, %2" : "=v"(pw1) : "v"(p2[0][2]), "v"(p2[0][3]));
        asm("v_cvt_pk_bf16_f32 %0, %1, %2" : "=v"(pw2) : "v"(p2[1][0]), "v"(p2[1][1]));
        asm("v_cvt_pk_bf16_f32 %0, %1, %2" : "=v"(pw3) : "v"(p2[1][2]), "v"(p2[1][3]));
        union { unsigned w[4]; s16x8 v; } pau;
        pau.w[0] = pw0; pau.w[1] = pw1; pau.w[2] = pw2; pau.w[3] = pw3;
        s16x8 pa = pau.v;

        __builtin_amdgcn_s_setprio(1);
#pragma unroll
        for (int nf = 0; nf < 8; ++nf) {
            int d = nf * 16 + lo;
            const char* vrow = (const char*)Vs[cur] + d * 64;
            int swz = (d & 3) << 4;
            int ob = hi << 3;
            s16x4 vlo = *(const s16x4*)(vrow + (ob ^ swz));
            s16x4 vhi = *(const s16x4*)(vrow + ((ob + 32) ^ swz));
            s16x8 vf = {vlo[0], vlo[1], vlo[2], vlo[3], vhi[0], vhi[1], vhi[2], vhi[3]};
            oacc[nf] = __builtin_amdgcn_mfma_f32_16x16x32_bf16(pa, vf, oacc[nf], 0, 0, 0);
        }
        __builtin_amdgcn_s_setprio(0);
    }

    if (hi == 0) {
        int mi = (half * 16 + bh) * 2048 + qrow;
        Mp[mi] = mrun;
        Lp[mi] = lrun;
    }
    u16* Op = half ? Op1 : Op0;
#pragma unroll
    for (int nf = 0; nf < 8; ++nf) {
        int d = nf * 16 + lo;
#pragma unroll
        for (int r = 0; r < 4; ++r) {
            int q2 = qt * 64 + wave * 16 + (hi << 2) + r;
            Op[((size_t)(b * 2048 + q2) << 10) + h * 128 + d] = f2bf(oacc[nf][r]);
        }
    }
}

// ---------------- combine partials + self-force -> Tb ----------------
__global__ __launch_bounds__(256) void attn_combine(
    const u16* __restrict__ O0, const u16* __restrict__ O1,
    const float* __restrict__ Mp, const float* __restrict__ Lp,
    const u16* __restrict__ Sb, u16* __restrict__ Tb) {
    int i = blockIdx.x * 256 + threadIdx.x;
    int d0 = (i & 15) << 3;
    int row = i >> 4;
    int h = row & 7;
    int bq = row >> 3;
    int b = bq >> 11, q = bq & 2047;
    int bh = b * 8 + h;
    int mi0 = bh * 2048 + q, mi1 = (16 + bh) * 2048 + q;
    float m0 = Mp[mi0], m1 = Mp[mi1], l0 = Lp[mi0], l1 = Lp[mi1];
    float m = fmaxf(m0, m1);
    float a0 = exp2f(m0 - m), a1 = exp2f(m1 - m);
    float rd = 1.0f / (l0 * a0 + l1 * a1);
    size_t base = ((size_t)bq << 10) + (h << 7) + d0;
    s16x8 o0 = *(const s16x8*)(O0 + base);
    s16x8 o1 = *(const s16x8*)(O1 + base);
    s16x8 sf = *(const s16x8*)(Sb + base);
    u16x8 out;
#pragma unroll
    for (int e = 0; e < 8; ++e)
        out[e] = f2bf((bf2f((u16)o0[e]) * a0 + bf2f((u16)o1[e]) * a1) * rd + bf2f((u16)sf[e]));
    *(u16x8*)(Tb + base) = out;
}

// ---------------- launch ----------------
extern "C" void kernel_launch(void* const* d_in, const int* in_sizes, int n_in,
                              void* d_out, int out_size, void* d_ws, size_t ws_size,
                              hipStream_t stream) {
    const float* x   = (const float*)d_in[0];
    const float* Wk  = (const float*)d_in[1];
    const float* Wv  = (const float*)d_in[2];
    const float* Wsf = (const float*)d_in[3];
    const float* Wo  = (const float*)d_in[4];
    float* out = (float*)d_out;
    char* ws = (char*)d_ws;
    u16* xb   = (u16*)(ws);                      // 8 MB (also O0part / Tb)
    u16* wcat = (u16*)(ws + (8u << 20));         // 6 MB [3072x1024]
    u16* Kb   = (u16*)(ws + (16u << 20));        // 8 MB
    u16* Vtb  = (u16*)(ws + (24u << 20));        // 8 MB, [BH][128][2048]
    u16* Sbf  = (u16*)(ws + (32u << 20));        // 8 MB
    u16* Tb   = xb;

    u16* wob   = (u16*)(ws + (40u << 20));       // 2 MB
    u16* Op0   = xb;
    u16* Op1   = (u16*)(ws + (8u << 20));        // over dead wcat
    float* Mp  = (float*)(ws + (42u << 20));
    float* Lp  = (float*)(ws + (42u << 20) + (256u << 10));

    cast_all<<<8192, 256, 0, stream>>>(x, Wk, Wv, Wsf, Wo,
                                       xb, wcat, wcat + (1u << 20), wcat + (2u << 20), wob);
    gemm8_proj<<<192, 512, 0, stream>>>(xb, wcat, Kb, Vtb, Sbf);
    attn_split<<<dim3(64, 16), 256, 0, stream>>>(Kb, Vtb, Op0, Op1, Mp, Lp);
    attn_combine<<<2048, 256, 0, stream>>>(Op0, Op1, Mp, Lp, Sbf, Tb);
    gemm_out<<<dim3(8, 32), 256, 0, stream>>>(Tb, wob, out);
}